// Round 3
// baseline (1775.736 us; speedup 1.0000x reference)
//
#include <hip/hip_runtime.h>
#include <cmath>

#define NB 800
#define BB 8
#define FF 12
#define DD 32
#define DIMM 40
#define KSEL 20

// two-step mul-add with contraction barrier: matches numpy's round(v + round(0.01*n))
__device__ __forceinline__ float score_f32(float v, float n) {
    float p = 0.01f * n;
    asm volatile("" : "+v"(p));
    return v + p;
}

// n = tanh(alpha * (emb @ W^T + b)) : (800,40)
__global__ __launch_bounds__(256) void lin_tanh_kernel(
    const float* __restrict__ emb, const float* __restrict__ W,
    const float* __restrict__ bias, const float* __restrict__ alphaP,
    float* __restrict__ out)
{
    int idx = blockIdx.x * 256 + threadIdx.x;
    if (idx >= NB * DIMM) return;
    int i = idx / DIMM, m = idx - i * DIMM;
    float acc = 0.f;
    #pragma unroll
    for (int d = 0; d < DIMM; ++d) acc += emb[i * DIMM + d] * W[m * DIMM + d];
    acc += bias[m];
    out[idx] = tanhf(alphaP[0] * acc);
}

// Fused adj1 + row top-K, f32 quantized scoring + lowest-index ties.
__global__ __launch_bounds__(256) void adj1_topk_kernel(
    const float* __restrict__ n1, const float* __restrict__ n2,
    const float* __restrict__ alphaP, const float* __restrict__ noise,
    float* __restrict__ a1d, float* __restrict__ a1val, int* __restrict__ a1idx)
{
    int i = blockIdx.x;
    int tid = threadIdx.x;
    __shared__ float vals[NB];
    __shared__ float sc[NB];
    __shared__ float msk[NB];
    __shared__ float redV[256];
    __shared__ int   redI[256];
    __shared__ int   sel[KSEL];
    __shared__ float n1i[DIMM], n2i[DIMM];
    if (tid < DIMM) { n1i[tid] = n1[i * DIMM + tid]; n2i[tid] = n2[i * DIMM + tid]; }
    __syncthreads();
    float alpha = alphaP[0];
    for (int j = tid; j < NB; j += 256) {
        float s1 = 0.f, s2 = 0.f;
        #pragma unroll
        for (int d = 0; d < DIMM; ++d) {
            s1 += n1i[d] * n2[j * DIMM + d];
            s2 += n2i[d] * n1[j * DIMM + d];
        }
        float t = tanhf(alpha * (s1 - s2));
        float v = t > 0.f ? t : 0.f;
        vals[j] = v;
        sc[j] = score_f32(v, noise[(size_t)i * NB + j]);
        msk[j] = 0.f;
    }
    __syncthreads();
    for (int t = 0; t < KSEL; ++t) {
        float bv = -2.0e30f; int bi = NB;
        for (int j = tid; j < NB; j += 256) {
            float s = sc[j];
            if (s > bv || (s == bv && j < bi)) { bv = s; bi = j; }
        }
        redV[tid] = bv; redI[tid] = bi;
        __syncthreads();
        for (int s2 = 128; s2 > 0; s2 >>= 1) {
            if (tid < s2) {
                float ov = redV[tid + s2]; int oi = redI[tid + s2];
                if (ov > redV[tid] || (ov == redV[tid] && oi < redI[tid])) {
                    redV[tid] = ov; redI[tid] = oi;
                }
            }
            __syncthreads();
        }
        if (tid == 0) { sel[t] = redI[0]; sc[redI[0]] = -1.0e30f; }
        __syncthreads();
    }
    if (tid < KSEL) msk[sel[tid]] = 1.f;
    __syncthreads();
    if (tid == 0) {
        // sort selected indices ascending so a3's gather-sum runs in k-order
        int tmp[KSEL];
        #pragma unroll
        for (int t = 0; t < KSEL; ++t) tmp[t] = sel[t];
        for (int a = 1; a < KSEL; ++a) {
            int key = tmp[a]; int b = a - 1;
            while (b >= 0 && tmp[b] > key) { tmp[b + 1] = tmp[b]; --b; }
            tmp[b + 1] = key;
        }
        for (int t = 0; t < KSEL; ++t) {
            a1idx[i * KSEL + t] = tmp[t];
            a1val[i * KSEL + t] = vals[tmp[t]];
        }
    }
    __syncthreads();
    for (int j = tid; j < NB; j += 256) a1d[(size_t)i * NB + j] = vals[j] * msk[j];
}

// Column-wise top-K mask for adj2 = M - M^T, f32 scoring + lowest-index ties.
__global__ __launch_bounds__(256) void topk_col_kernel(
    const float* __restrict__ In, const float* __restrict__ noise,
    float* __restrict__ Out)
{
    int j = blockIdx.x;
    int b = blockIdx.y;
    int tid = threadIdx.x;
    const float* Ib = In + (size_t)b * NB * NB;
    const float* nb = noise + (size_t)b * NB * NB;
    __shared__ float vals[NB];
    __shared__ float sc[NB];
    __shared__ float redV[256];
    __shared__ int   redI[256];
    __shared__ int   sel[KSEL];
    for (int i = tid; i < NB; i += 256) {
        float v = Ib[(size_t)i * NB + j] - Ib[(size_t)j * NB + i];
        vals[i] = v;
        sc[i] = score_f32(v, nb[(size_t)i * NB + j]);
    }
    __syncthreads();
    for (int t = 0; t < KSEL; ++t) {
        float bv = -2.0e30f; int bi = NB;
        for (int i = tid; i < NB; i += 256) {
            float s = sc[i];
            if (s > bv || (s == bv && i < bi)) { bv = s; bi = i; }
        }
        redV[tid] = bv; redI[tid] = bi;
        __syncthreads();
        for (int s2 = 128; s2 > 0; s2 >>= 1) {
            if (tid < s2) {
                float ov = redV[tid + s2]; int oi = redI[tid + s2];
                if (ov > redV[tid] || (ov == redV[tid] && oi < redI[tid])) {
                    redV[tid] = ov; redI[tid] = oi;
                }
            }
            __syncthreads();
        }
        if (tid == 0) { sel[t] = redI[0]; sc[redI[0]] = -1.0e30f; }
        __syncthreads();
    }
    for (int i = tid; i < NB; i += 256) sc[i] = 0.f;
    __syncthreads();
    if (tid < KSEL) sc[sel[tid]] = 1.f;
    __syncthreads();
    float* Ob = Out + (size_t)b * NB * NB;
    for (int i = tid; i < NB; i += 256) Ob[(size_t)i * NB + j] = vals[i] * sc[i];
}

// Fused a3 + column top-K, f32 (values are exactly {0,1} — ranking is quantized noise).
__global__ __launch_bounds__(256) void a3_topk_kernel(
    const float* __restrict__ a2, const float* __restrict__ a1val,
    const int* __restrict__ a1idx, const float* __restrict__ alphaP,
    const float* __restrict__ noise, float* __restrict__ a3)
{
    int e = blockIdx.x, b = blockIdx.y;
    int tid = threadIdx.x;
    const float* a2b = a2 + (size_t)b * NB * NB;
    const float* nzb = noise + (size_t)b * NB * NB;
    __shared__ float vals[NB];
    __shared__ float sc[NB];
    __shared__ float msk[NB];
    __shared__ float redV[256];
    __shared__ int   redI[256];
    __shared__ int   sel[KSEL];
    float alpha = alphaP[0];
    for (int i = tid; i < NB; i += 256) {
        float x = 0.f;
        const float* av = a1val + i * KSEL;
        const int*   ai = a1idx + i * KSEL;
        #pragma unroll
        for (int t = 0; t < KSEL; ++t)
            x = fmaf(av[t], a2b[(size_t)ai[t] * NB + e], x);
        float th = tanhf(alpha * x);
        float v = th > 0.f ? th : 0.f;
        vals[i] = v;
        sc[i] = score_f32(v, nzb[(size_t)i * NB + e]);
        msk[i] = 0.f;
    }
    __syncthreads();
    for (int t = 0; t < KSEL; ++t) {
        float bv = -2.0e30f; int bi = NB;
        for (int i = tid; i < NB; i += 256) {
            float s = sc[i];
            if (s > bv || (s == bv && i < bi)) { bv = s; bi = i; }
        }
        redV[tid] = bv; redI[tid] = bi;
        __syncthreads();
        for (int s2 = 128; s2 > 0; s2 >>= 1) {
            if (tid < s2) {
                float ov = redV[tid + s2]; int oi = redI[tid + s2];
                if (ov > redV[tid] || (ov == redV[tid] && oi < redI[tid])) {
                    redV[tid] = ov; redI[tid] = oi;
                }
            }
            __syncthreads();
        }
        if (tid == 0) { sel[t] = redI[0]; sc[redI[0]] = -1.0e30f; }
        __syncthreads();
    }
    if (tid < KSEL) msk[sel[tid]] = 1.f;
    __syncthreads();
    float* a3b = a3 + (size_t)b * NB * NB;
    for (int i = tid; i < NB; i += 256) a3b[(size_t)i * NB + e] = vals[i] * msk[i];
}

// v[b,i,j] = tanh( (sum_f sum_d x[b,f,i,d]*x[b,f,j,d]) / F )
__global__ __launch_bounds__(256) void vgram_kernel(
    const float* __restrict__ x, float* __restrict__ v)
{
    int b = blockIdx.z;
    int i0 = blockIdx.y * 32, j0 = blockIdx.x * 32;
    int tx = threadIdx.x, ty = threadIdx.y;
    int t = ty * 16 + tx;
    __shared__ float Xi[32][DD + 1];
    __shared__ float Xj[32][DD + 1];
    float acc00 = 0.f, acc01 = 0.f, acc10 = 0.f, acc11 = 0.f;
    for (int f = 0; f < FF; ++f) {
        const float* base = x + ((size_t)b * FF + f) * NB * DD;
        #pragma unroll
        for (int l = 0; l < 4; ++l) {
            int e = t + l * 256;
            int r = e >> 5, c = e & 31;
            Xi[r][c] = base[(size_t)(i0 + r) * DD + c];
            Xj[r][c] = base[(size_t)(j0 + r) * DD + c];
        }
        __syncthreads();
        #pragma unroll
        for (int d = 0; d < DD; ++d) {
            float a0 = Xi[2 * ty][d], a1 = Xi[2 * ty + 1][d];
            float b0 = Xj[2 * tx][d], b1 = Xj[2 * tx + 1][d];
            acc00 += a0 * b0; acc01 += a0 * b1;
            acc10 += a1 * b0; acc11 += a1 * b1;
        }
        __syncthreads();
    }
    size_t basev = (size_t)b * NB * NB;
    v[basev + (size_t)(i0 + 2 * ty) * NB + j0 + 2 * tx]         = tanhf(acc00 / 12.0f);
    v[basev + (size_t)(i0 + 2 * ty) * NB + j0 + 2 * tx + 1]     = tanhf(acc01 / 12.0f);
    v[basev + (size_t)(i0 + 2 * ty + 1) * NB + j0 + 2 * tx]     = tanhf(acc10 / 12.0f);
    v[basev + (size_t)(i0 + 2 * ty + 1) * NB + j0 + 2 * tx + 1] = tanhf(acc11 / 12.0f);
}

// C[b,i,j] = sum_k A[b,i,k]*B[b,j,k] (+bias[j]), replicated nCopies times.
__global__ __launch_bounds__(256) void gemm_abt_kernel(
    const float* __restrict__ A, const float* __restrict__ B,
    const float* __restrict__ bias, float* __restrict__ C,
    int M, int Nn, int Kk,
    long aStride, long bStride, long cStride,
    int nCopies, long copyStride)
{
    int bz = blockIdx.z;
    const float* Ab = A + (size_t)bz * aStride;
    const float* Bb = B + (size_t)bz * bStride;
    float* Cb = C + (size_t)bz * cStride;
    int i0 = blockIdx.y * 64, j0 = blockIdx.x * 64;
    int tx = threadIdx.x, ty = threadIdx.y;
    int tid = ty * 16 + tx;
    __shared__ float As[64][17];
    __shared__ float Bs[64][17];
    float acc[4][4] = {};
    int lr = tid >> 2;
    int lc = (tid & 3) * 4;
    for (int kt = 0; kt < Kk; kt += 16) {
        int ai = i0 + lr;
        float4 va = make_float4(0.f, 0.f, 0.f, 0.f);
        if (ai < M) va = *(const float4*)(Ab + (size_t)ai * Kk + kt + lc);
        As[lr][lc] = va.x; As[lr][lc + 1] = va.y; As[lr][lc + 2] = va.z; As[lr][lc + 3] = va.w;
        int bj = j0 + lr;
        float4 vb = make_float4(0.f, 0.f, 0.f, 0.f);
        if (bj < Nn) vb = *(const float4*)(Bb + (size_t)bj * Kk + kt + lc);
        Bs[lr][lc] = vb.x; Bs[lr][lc + 1] = vb.y; Bs[lr][lc + 2] = vb.z; Bs[lr][lc + 3] = vb.w;
        __syncthreads();
        #pragma unroll
        for (int kk = 0; kk < 16; ++kk) {
            float ar0 = As[ty * 4][kk], ar1 = As[ty * 4 + 1][kk];
            float ar2 = As[ty * 4 + 2][kk], ar3 = As[ty * 4 + 3][kk];
            float br0 = Bs[tx * 4][kk], br1 = Bs[tx * 4 + 1][kk];
            float br2 = Bs[tx * 4 + 2][kk], br3 = Bs[tx * 4 + 3][kk];
            acc[0][0] += ar0 * br0; acc[0][1] += ar0 * br1; acc[0][2] += ar0 * br2; acc[0][3] += ar0 * br3;
            acc[1][0] += ar1 * br0; acc[1][1] += ar1 * br1; acc[1][2] += ar1 * br2; acc[1][3] += ar1 * br3;
            acc[2][0] += ar2 * br0; acc[2][1] += ar2 * br1; acc[2][2] += ar2 * br2; acc[2][3] += ar2 * br3;
            acc[3][0] += ar3 * br0; acc[3][1] += ar3 * br1; acc[3][2] += ar3 * br2; acc[3][3] += ar3 * br3;
        }
        __syncthreads();
    }
    #pragma unroll
    for (int m = 0; m < 4; ++m) {
        int i = i0 + ty * 4 + m;
        if (i >= M) continue;
        #pragma unroll
        for (int n = 0; n < 4; ++n) {
            int j = j0 + tx * 4 + n;
            if (j >= Nn) continue;
            float v = acc[m][n] + (bias ? bias[j] : 0.f);
            for (int c = 0; c < nCopies; ++c)
                Cb[(size_t)c * copyStride + (size_t)i * Nn + j] = v;
        }
    }
}

// Per-node attention over the batch axis (q-independent).
__global__ __launch_bounds__(256) void attn_kernel(
    const float* __restrict__ Qn, const float* __restrict__ Kp,
    const float* __restrict__ V, float* __restrict__ O)
{
    int n = blockIdx.x;
    int tid = threadIdx.x;
    float loc[BB];
    #pragma unroll
    for (int k = 0; k < BB; ++k) loc[k] = 0.f;
    const float* q = Qn + (size_t)n * NB;
    for (int e = tid; e < NB; e += 256) {
        float qv = q[e];
        #pragma unroll
        for (int k = 0; k < BB; ++k) loc[k] += qv * Kp[((size_t)k * NB + n) * NB + e];
    }
    __shared__ float red[BB][256];
    #pragma unroll
    for (int k = 0; k < BB; ++k) red[k][tid] = loc[k];
    __syncthreads();
    for (int s = 128; s > 0; s >>= 1) {
        if (tid < s) {
            #pragma unroll
            for (int k = 0; k < BB; ++k) red[k][tid] += red[k][tid + s];
        }
        __syncthreads();
    }
    __shared__ float w[BB];
    if (tid == 0) {
        float s[BB];
        float mx = -INFINITY;
        for (int k = 0; k < BB; ++k) { s[k] = red[k][0] / sqrtf(800.0f); if (s[k] > mx) mx = s[k]; }
        float sum = 0.f;
        for (int k = 0; k < BB; ++k) { float e = expf(s[k] - mx); w[k] = e; sum += e; }
        for (int k = 0; k < BB; ++k) w[k] /= sum;
    }
    __syncthreads();
    float wl[BB];
    #pragma unroll
    for (int k = 0; k < BB; ++k) wl[k] = w[k];
    for (int e = tid; e < NB; e += 256) {
        float acc = 0.f;
        #pragma unroll
        for (int k = 0; k < BB; ++k) acc += wl[k] * V[((size_t)k * NB + n) * NB + e];
        O[(size_t)n * NB + e] = acc;
    }
}

extern "C" void kernel_launch(void* const* d_in, const int* in_sizes, int n_in,
                              void* d_out, int out_size, void* d_ws, size_t ws_size,
                              hipStream_t stream)
{
    const float* tfeat      = (const float*)d_in[0];
    const float* dfeat      = (const float*)d_in[1];
    const float* alphaP     = (const float*)d_in[2];
    const float* emb1       = (const float*)d_in[3];
    const float* emb2       = (const float*)d_in[4];
    const float* lin1_w     = (const float*)d_in[5];
    const float* lin1_b     = (const float*)d_in[6];
    const float* lin2_w     = (const float*)d_in[7];
    const float* lin2_b     = (const float*)d_in[8];
    const float* in_proj_w  = (const float*)d_in[9];
    const float* in_proj_b  = (const float*)d_in[10];
    const float* out_proj_w = (const float*)d_in[11];
    const float* out_proj_b = (const float*)d_in[12];
    const float* noise1     = (const float*)d_in[13];
    const float* noise2     = (const float*)d_in[14];
    const float* noise3     = (const float*)d_in[15];
    float* out = (float*)d_out;

    const size_t NN  = (size_t)NB * NB;   // 640000
    const size_t BNN = (size_t)BB * NN;   // 5120000

    float* ws  = (float*)d_ws;
    float* v1  = ws;             // BNN   (later reused as a3)
    float* v2  = v1 + BNN;       // BNN
    float* Mb  = v2 + BNN;       // BNN   (M, later reused as Kp)
    float* n1  = Mb + BNN;       // 32000
    float* n2  = n1 + NB * DIMM; // 32000
    float* a1d = n2 + NB * DIMM; // NN (dense masked a1)
    float* Qn  = a1d + NN;       // NN
    float* Ob  = Qn + NN;        // NN
    float* a1v = Ob + NN;        // 16000
    int*   a1i = (int*)(a1v + NB * KSEL); // 16000 ints
    float* a3  = v1;             // reuse (v1 dead after M)
    float* Kp  = Mb;             // reuse (M dead after topk2)
    float* a2  = out;            // d_out as scratch (a2, then V)
    float* Vb  = out;

    const float* Wq = in_proj_w;
    const float* Wk = in_proj_w + NN;
    const float* Wv = in_proj_w + 2 * NN;
    const float* bq = in_proj_b;
    const float* bk = in_proj_b + NB;
    const float* bv = in_proj_b + 2 * NB;

    lin_tanh_kernel<<<(NB * DIMM + 255) / 256, 256, 0, stream>>>(emb1, lin1_w, lin1_b, alphaP, n1);
    lin_tanh_kernel<<<(NB * DIMM + 255) / 256, 256, 0, stream>>>(emb2, lin2_w, lin2_b, alphaP, n2);
    adj1_topk_kernel<<<NB, 256, 0, stream>>>(n1, n2, alphaP, noise1, a1d, a1v, a1i);
    vgram_kernel<<<dim3(25, 25, BB), dim3(16, 16), 0, stream>>>(tfeat, v1);
    vgram_kernel<<<dim3(25, 25, BB), dim3(16, 16), 0, stream>>>(dfeat, v2);
    gemm_abt_kernel<<<dim3(13, 13, BB), dim3(16, 16), 0, stream>>>(
        v1, v2, nullptr, Mb, NB, NB, NB, (long)NN, (long)NN, (long)NN, 1, 0);
    topk_col_kernel<<<dim3(NB, BB), 256, 0, stream>>>(Mb, noise2, a2);
    a3_topk_kernel<<<dim3(NB, BB), 256, 0, stream>>>(a2, a1v, a1i, alphaP, noise3, a3);
    gemm_abt_kernel<<<dim3(13, 13, 1), dim3(16, 16), 0, stream>>>(
        a1d, Wq, bq, Qn, NB, NB, NB, 0, 0, 0, 1, 0);
    gemm_abt_kernel<<<dim3(13, 13, BB), dim3(16, 16), 0, stream>>>(
        a2, Wk, bk, Kp, NB, NB, NB, (long)NN, 0, (long)NN, 1, 0);
    gemm_abt_kernel<<<dim3(13, 13, BB), dim3(16, 16), 0, stream>>>(
        a3, Wv, bv, Vb, NB, NB, NB, (long)NN, 0, (long)NN, 1, 0);
    attn_kernel<<<NB, 256, 0, stream>>>(Qn, Kp, Vb, Ob);
    gemm_abt_kernel<<<dim3(13, 13, 1), dim3(16, 16), 0, stream>>>(
        Ob, out_proj_w, out_proj_b, out, NB, NB, NB, 0, 0, 0, BB, (long)NN);
}

// Round 4
// 1519.925 us; speedup vs baseline: 1.1683x; 1.1683x over previous
//
#include <hip/hip_runtime.h>
#include <cmath>

#define NB 800
#define BB 8
#define FF 12
#define DD 32
#define DIMM 40
#define KSEL 20
#define NN_ ((size_t)NB * NB)

// two-step mul-add with contraction barrier: matches numpy's round(v + round(0.01*n))
__device__ __forceinline__ float score_f32(float v, float n) {
    float p = 0.01f * n;
    asm volatile("" : "+v"(p));
    return v + p;
}

// n = tanh(alpha * (emb @ W^T + b)) : (800,40)
__global__ __launch_bounds__(256) void lin_tanh_kernel(
    const float* __restrict__ emb, const float* __restrict__ W,
    const float* __restrict__ bias, const float* __restrict__ alphaP,
    float* __restrict__ out)
{
    int idx = blockIdx.x * 256 + threadIdx.x;
    if (idx >= NB * DIMM) return;
    int i = idx / DIMM, m = idx - i * DIMM;
    float acc = 0.f;
    #pragma unroll
    for (int d = 0; d < DIMM; ++d) acc += emb[i * DIMM + d] * W[m * DIMM + d];
    acc += bias[m];
    out[idx] = tanhf(alphaP[0] * acc);
}

// Fused adj1 + row top-K, f32 quantized scoring + lowest-index ties.
__global__ __launch_bounds__(256) void adj1_topk_kernel(
    const float* __restrict__ n1, const float* __restrict__ n2,
    const float* __restrict__ alphaP, const float* __restrict__ noise,
    float* __restrict__ a1d, float* __restrict__ a1val, int* __restrict__ a1idx)
{
    int i = blockIdx.x;
    int tid = threadIdx.x;
    __shared__ float vals[NB];
    __shared__ float sc[NB];
    __shared__ float msk[NB];
    __shared__ float redV[256];
    __shared__ int   redI[256];
    __shared__ int   sel[KSEL];
    __shared__ float n1i[DIMM], n2i[DIMM];
    if (tid < DIMM) { n1i[tid] = n1[i * DIMM + tid]; n2i[tid] = n2[i * DIMM + tid]; }
    __syncthreads();
    float alpha = alphaP[0];
    for (int j = tid; j < NB; j += 256) {
        float s1 = 0.f, s2 = 0.f;
        #pragma unroll
        for (int d = 0; d < DIMM; ++d) {
            s1 += n1i[d] * n2[j * DIMM + d];
            s2 += n2i[d] * n1[j * DIMM + d];
        }
        float t = tanhf(alpha * (s1 - s2));
        float v = t > 0.f ? t : 0.f;
        vals[j] = v;
        sc[j] = score_f32(v, noise[(size_t)i * NB + j]);
        msk[j] = 0.f;
    }
    __syncthreads();
    for (int t = 0; t < KSEL; ++t) {
        float bv = -2.0e30f; int bi = NB;
        for (int j = tid; j < NB; j += 256) {
            float s = sc[j];
            if (s > bv || (s == bv && j < bi)) { bv = s; bi = j; }
        }
        redV[tid] = bv; redI[tid] = bi;
        __syncthreads();
        for (int s2 = 128; s2 > 0; s2 >>= 1) {
            if (tid < s2) {
                float ov = redV[tid + s2]; int oi = redI[tid + s2];
                if (ov > redV[tid] || (ov == redV[tid] && oi < redI[tid])) {
                    redV[tid] = ov; redI[tid] = oi;
                }
            }
            __syncthreads();
        }
        if (tid == 0) { sel[t] = redI[0]; sc[redI[0]] = -1.0e30f; }
        __syncthreads();
    }
    if (tid < KSEL) msk[sel[tid]] = 1.f;
    __syncthreads();
    if (tid == 0) {
        int tmp[KSEL];
        #pragma unroll
        for (int t = 0; t < KSEL; ++t) tmp[t] = sel[t];
        for (int a = 1; a < KSEL; ++a) {
            int key = tmp[a]; int b = a - 1;
            while (b >= 0 && tmp[b] > key) { tmp[b + 1] = tmp[b]; --b; }
            tmp[b + 1] = key;
        }
        for (int t = 0; t < KSEL; ++t) {
            a1idx[i * KSEL + t] = tmp[t];
            a1val[i * KSEL + t] = vals[tmp[t]];
        }
    }
    __syncthreads();
    for (int j = tid; j < NB; j += 256) a1d[(size_t)i * NB + j] = vals[j] * msk[j];
}

// In-place antisymmetrization: M <- M - M^T (per batch), 32x32 tile pairs.
__global__ __launch_bounds__(256) void antisym_kernel(float* __restrict__ M)
{
    int ti = blockIdx.x, tj = blockIdx.y, b = blockIdx.z;
    if (ti > tj) return;
    float* Mb_ = M + (size_t)b * NN_;
    __shared__ float T1[32][33];
    __shared__ float T2[32][33];
    int tid = threadIdx.x;
    int r = tid >> 3, c4 = (tid & 7) * 4;
    int i0 = ti * 32, j0 = tj * 32;
    float4 x1 = *(const float4*)(Mb_ + (size_t)(i0 + r) * NB + j0 + c4);
    float4 x2 = *(const float4*)(Mb_ + (size_t)(j0 + r) * NB + i0 + c4);
    T1[r][c4] = x1.x; T1[r][c4 + 1] = x1.y; T1[r][c4 + 2] = x1.z; T1[r][c4 + 3] = x1.w;
    T2[r][c4] = x2.x; T2[r][c4 + 1] = x2.y; T2[r][c4 + 2] = x2.z; T2[r][c4 + 3] = x2.w;
    __syncthreads();
    float4 d1;
    d1.x = T1[r][c4 + 0] - T2[c4 + 0][r];
    d1.y = T1[r][c4 + 1] - T2[c4 + 1][r];
    d1.z = T1[r][c4 + 2] - T2[c4 + 2][r];
    d1.w = T1[r][c4 + 3] - T2[c4 + 3][r];
    *(float4*)(Mb_ + (size_t)(i0 + r) * NB + j0 + c4) = d1;
    if (ti != tj) {
        float4 d2;
        d2.x = T2[r][c4 + 0] - T1[c4 + 0][r];
        d2.y = T2[r][c4 + 1] - T1[c4 + 1][r];
        d2.z = T2[r][c4 + 2] - T1[c4 + 2][r];
        d2.w = T2[r][c4 + 3] - T1[c4 + 3][r];
        *(float4*)(Mb_ + (size_t)(j0 + r) * NB + i0 + c4) = d2;
    }
}

// 8-column-tile top-K scan: 8 groups x 32 lanes, 20 rounds of lexicographic
// argmax (score desc, index asc). Tombstone -1e30 marks selected entries.
__device__ __forceinline__ void topk_scan8(float (*sc)[9], int tid)
{
    int g = tid >> 5;
    int l = tid & 31;
    for (int t = 0; t < KSEL; ++t) {
        float bv = -2.0e30f; int bi = NB;
        for (int i = l; i < NB; i += 32) {
            float s = sc[i][g];
            if (s > bv || (s == bv && i < bi)) { bv = s; bi = i; }
        }
        #pragma unroll
        for (int m = 16; m >= 1; m >>= 1) {
            float ov = __shfl_xor(bv, m, 32);
            int   oi = __shfl_xor(bi, m, 32);
            if (ov > bv || (ov == bv && oi < bi)) { bv = ov; bi = oi; }
        }
        if (l == 0) sc[bi][g] = -1.0e30f;
        __syncthreads();
    }
}

// Column top-K of adj2 (already antisymmetrized), 8 columns per block.
__global__ __launch_bounds__(256) void topk2_tile_kernel(
    const float* __restrict__ adj2, const float* __restrict__ noise,
    float* __restrict__ outp)
{
    int j0 = blockIdx.x * 8;
    int b = blockIdx.y;
    int tid = threadIdx.x;
    const float* Ab = adj2 + (size_t)b * NN_;
    const float* Zb = noise + (size_t)b * NN_;
    float* Ob = outp + (size_t)b * NN_;
    __shared__ float sc[NB][9];
    __shared__ float vals[NB][9];
    int c2 = tid & 1, i0 = tid >> 1;
    for (int i = i0; i < NB; i += 128) {
        float4 v  = *(const float4*)(Ab + (size_t)i * NB + j0 + c2 * 4);
        float4 nz = *(const float4*)(Zb + (size_t)i * NB + j0 + c2 * 4);
        int c = c2 * 4;
        vals[i][c + 0] = v.x; vals[i][c + 1] = v.y; vals[i][c + 2] = v.z; vals[i][c + 3] = v.w;
        sc[i][c + 0] = score_f32(v.x, nz.x);
        sc[i][c + 1] = score_f32(v.y, nz.y);
        sc[i][c + 2] = score_f32(v.z, nz.z);
        sc[i][c + 3] = score_f32(v.w, nz.w);
    }
    __syncthreads();
    topk_scan8(sc, tid);
    for (int i = i0; i < NB; i += 128) {
        int c = c2 * 4;
        float4 o;
        o.x = vals[i][c + 0] * (sc[i][c + 0] == -1.0e30f ? 1.f : 0.f);
        o.y = vals[i][c + 1] * (sc[i][c + 1] == -1.0e30f ? 1.f : 0.f);
        o.z = vals[i][c + 2] * (sc[i][c + 2] == -1.0e30f ? 1.f : 0.f);
        o.w = vals[i][c + 3] * (sc[i][c + 3] == -1.0e30f ? 1.f : 0.f);
        *(float4*)(Ob + (size_t)i * NB + j0 + c2 * 4) = o;
    }
}

// Fused a3 values (sparse a1 gather-GEMM, fmaf ascending-t chain) + column
// top-K, 8 columns per block.
__global__ __launch_bounds__(256) void a3_tile_kernel(
    const float* __restrict__ a2, const float* __restrict__ a1val,
    const int* __restrict__ a1idx, const float* __restrict__ alphaP,
    const float* __restrict__ noise, float* __restrict__ a3)
{
    int j0 = blockIdx.x * 8;
    int b = blockIdx.y;
    int tid = threadIdx.x;
    const float* a2b = a2 + (size_t)b * NN_;
    const float* Zb  = noise + (size_t)b * NN_;
    float* Ob = a3 + (size_t)b * NN_;
    __shared__ float sc[NB][9];
    __shared__ float vals[NB][9];
    float alpha = alphaP[0];
    int c2 = tid & 1, i0 = tid >> 1;
    for (int i = i0; i < NB; i += 128) {
        const float* av = a1val + i * KSEL;
        const int*   ai = a1idx + i * KSEL;
        float4 acc = make_float4(0.f, 0.f, 0.f, 0.f);
        #pragma unroll
        for (int t = 0; t < KSEL; ++t) {
            float vt = av[t];
            float4 s = *(const float4*)(a2b + (size_t)ai[t] * NB + j0 + c2 * 4);
            acc.x = fmaf(vt, s.x, acc.x);
            acc.y = fmaf(vt, s.y, acc.y);
            acc.z = fmaf(vt, s.z, acc.z);
            acc.w = fmaf(vt, s.w, acc.w);
        }
        float4 th;
        th.x = tanhf(alpha * acc.x); th.y = tanhf(alpha * acc.y);
        th.z = tanhf(alpha * acc.z); th.w = tanhf(alpha * acc.w);
        th.x = th.x > 0.f ? th.x : 0.f;
        th.y = th.y > 0.f ? th.y : 0.f;
        th.z = th.z > 0.f ? th.z : 0.f;
        th.w = th.w > 0.f ? th.w : 0.f;
        float4 nz = *(const float4*)(Zb + (size_t)i * NB + j0 + c2 * 4);
        int c = c2 * 4;
        vals[i][c + 0] = th.x; vals[i][c + 1] = th.y; vals[i][c + 2] = th.z; vals[i][c + 3] = th.w;
        sc[i][c + 0] = score_f32(th.x, nz.x);
        sc[i][c + 1] = score_f32(th.y, nz.y);
        sc[i][c + 2] = score_f32(th.z, nz.z);
        sc[i][c + 3] = score_f32(th.w, nz.w);
    }
    __syncthreads();
    topk_scan8(sc, tid);
    for (int i = i0; i < NB; i += 128) {
        int c = c2 * 4;
        float4 o;
        o.x = vals[i][c + 0] * (sc[i][c + 0] == -1.0e30f ? 1.f : 0.f);
        o.y = vals[i][c + 1] * (sc[i][c + 1] == -1.0e30f ? 1.f : 0.f);
        o.z = vals[i][c + 2] * (sc[i][c + 2] == -1.0e30f ? 1.f : 0.f);
        o.w = vals[i][c + 3] * (sc[i][c + 3] == -1.0e30f ? 1.f : 0.f);
        *(float4*)(Ob + (size_t)i * NB + j0 + c2 * 4) = o;
    }
}

// v[b,i,j] = tanh( (sum_f sum_d x[b,f,i,d]*x[b,f,j,d]) / F )
__global__ __launch_bounds__(256) void vgram_kernel(
    const float* __restrict__ x, float* __restrict__ v)
{
    int b = blockIdx.z;
    int i0 = blockIdx.y * 32, j0 = blockIdx.x * 32;
    int tx = threadIdx.x, ty = threadIdx.y;
    int t = ty * 16 + tx;
    __shared__ float Xi[32][DD + 1];
    __shared__ float Xj[32][DD + 1];
    float acc00 = 0.f, acc01 = 0.f, acc10 = 0.f, acc11 = 0.f;
    for (int f = 0; f < FF; ++f) {
        const float* base = x + ((size_t)b * FF + f) * NB * DD;
        #pragma unroll
        for (int l = 0; l < 4; ++l) {
            int e = t + l * 256;
            int r = e >> 5, c = e & 31;
            Xi[r][c] = base[(size_t)(i0 + r) * DD + c];
            Xj[r][c] = base[(size_t)(j0 + r) * DD + c];
        }
        __syncthreads();
        #pragma unroll
        for (int d = 0; d < DD; ++d) {
            float a0 = Xi[2 * ty][d], a1 = Xi[2 * ty + 1][d];
            float b0 = Xj[2 * tx][d], b1 = Xj[2 * tx + 1][d];
            acc00 += a0 * b0; acc01 += a0 * b1;
            acc10 += a1 * b0; acc11 += a1 * b1;
        }
        __syncthreads();
    }
    size_t basev = (size_t)b * NN_;
    v[basev + (size_t)(i0 + 2 * ty) * NB + j0 + 2 * tx]         = tanhf(acc00 / 12.0f);
    v[basev + (size_t)(i0 + 2 * ty) * NB + j0 + 2 * tx + 1]     = tanhf(acc01 / 12.0f);
    v[basev + (size_t)(i0 + 2 * ty + 1) * NB + j0 + 2 * tx]     = tanhf(acc10 / 12.0f);
    v[basev + (size_t)(i0 + 2 * ty + 1) * NB + j0 + 2 * tx + 1] = tanhf(acc11 / 12.0f);
}

// C[b,i,j] = sum_k A[b,i,k]*B[b,j,k] (+bias[j]), replicated nCopies times.
__global__ __launch_bounds__(256) void gemm_abt_kernel(
    const float* __restrict__ A, const float* __restrict__ B,
    const float* __restrict__ bias, float* __restrict__ C,
    int M, int Nn, int Kk,
    long aStride, long bStride, long cStride,
    int nCopies, long copyStride)
{
    int bz = blockIdx.z;
    const float* Ab = A + (size_t)bz * aStride;
    const float* Bb = B + (size_t)bz * bStride;
    float* Cb = C + (size_t)bz * cStride;
    int i0 = blockIdx.y * 64, j0 = blockIdx.x * 64;
    int tx = threadIdx.x, ty = threadIdx.y;
    int tid = ty * 16 + tx;
    __shared__ float As[64][17];
    __shared__ float Bs[64][17];
    float acc[4][4] = {};
    int lr = tid >> 2;
    int lc = (tid & 3) * 4;
    for (int kt = 0; kt < Kk; kt += 16) {
        int ai = i0 + lr;
        float4 va = make_float4(0.f, 0.f, 0.f, 0.f);
        if (ai < M) va = *(const float4*)(Ab + (size_t)ai * Kk + kt + lc);
        As[lr][lc] = va.x; As[lr][lc + 1] = va.y; As[lr][lc + 2] = va.z; As[lr][lc + 3] = va.w;
        int bj = j0 + lr;
        float4 vb = make_float4(0.f, 0.f, 0.f, 0.f);
        if (bj < Nn) vb = *(const float4*)(Bb + (size_t)bj * Kk + kt + lc);
        Bs[lr][lc] = vb.x; Bs[lr][lc + 1] = vb.y; Bs[lr][lc + 2] = vb.z; Bs[lr][lc + 3] = vb.w;
        __syncthreads();
        #pragma unroll
        for (int kk = 0; kk < 16; ++kk) {
            float ar0 = As[ty * 4][kk], ar1 = As[ty * 4 + 1][kk];
            float ar2 = As[ty * 4 + 2][kk], ar3 = As[ty * 4 + 3][kk];
            float br0 = Bs[tx * 4][kk], br1 = Bs[tx * 4 + 1][kk];
            float br2 = Bs[tx * 4 + 2][kk], br3 = Bs[tx * 4 + 3][kk];
            acc[0][0] += ar0 * br0; acc[0][1] += ar0 * br1; acc[0][2] += ar0 * br2; acc[0][3] += ar0 * br3;
            acc[1][0] += ar1 * br0; acc[1][1] += ar1 * br1; acc[1][2] += ar1 * br2; acc[1][3] += ar1 * br3;
            acc[2][0] += ar2 * br0; acc[2][1] += ar2 * br1; acc[2][2] += ar2 * br2; acc[2][3] += ar2 * br3;
            acc[3][0] += ar3 * br0; acc[3][1] += ar3 * br1; acc[3][2] += ar3 * br2; acc[3][3] += ar3 * br3;
        }
        __syncthreads();
    }
    #pragma unroll
    for (int m = 0; m < 4; ++m) {
        int i = i0 + ty * 4 + m;
        if (i >= M) continue;
        #pragma unroll
        for (int n = 0; n < 4; ++n) {
            int j = j0 + tx * 4 + n;
            if (j >= Nn) continue;
            float v = acc[m][n] + (bias ? bias[j] : 0.f);
            for (int c = 0; c < nCopies; ++c)
                Cb[(size_t)c * copyStride + (size_t)i * Nn + j] = v;
        }
    }
}

// Per-node attention over the batch axis (q-independent).
__global__ __launch_bounds__(256) void attn_kernel(
    const float* __restrict__ Qn, const float* __restrict__ Kp,
    const float* __restrict__ V, float* __restrict__ O)
{
    int n = blockIdx.x;
    int tid = threadIdx.x;
    float loc[BB];
    #pragma unroll
    for (int k = 0; k < BB; ++k) loc[k] = 0.f;
    const float* q = Qn + (size_t)n * NB;
    for (int e = tid; e < NB; e += 256) {
        float qv = q[e];
        #pragma unroll
        for (int k = 0; k < BB; ++k) loc[k] += qv * Kp[((size_t)k * NB + n) * NB + e];
    }
    __shared__ float red[BB][256];
    #pragma unroll
    for (int k = 0; k < BB; ++k) red[k][tid] = loc[k];
    __syncthreads();
    for (int s = 128; s > 0; s >>= 1) {
        if (tid < s) {
            #pragma unroll
            for (int k = 0; k < BB; ++k) red[k][tid] += red[k][tid + s];
        }
        __syncthreads();
    }
    __shared__ float w[BB];
    if (tid == 0) {
        float s[BB];
        float mx = -INFINITY;
        for (int k = 0; k < BB; ++k) { s[k] = red[k][0] / sqrtf(800.0f); if (s[k] > mx) mx = s[k]; }
        float sum = 0.f;
        for (int k = 0; k < BB; ++k) { float e = expf(s[k] - mx); w[k] = e; sum += e; }
        for (int k = 0; k < BB; ++k) w[k] /= sum;
    }
    __syncthreads();
    float wl[BB];
    #pragma unroll
    for (int k = 0; k < BB; ++k) wl[k] = w[k];
    for (int e = tid; e < NB; e += 256) {
        float acc = 0.f;
        #pragma unroll
        for (int k = 0; k < BB; ++k) acc += wl[k] * V[((size_t)k * NB + n) * NB + e];
        O[(size_t)n * NB + e] = acc;
    }
}

extern "C" void kernel_launch(void* const* d_in, const int* in_sizes, int n_in,
                              void* d_out, int out_size, void* d_ws, size_t ws_size,
                              hipStream_t stream)
{
    const float* tfeat      = (const float*)d_in[0];
    const float* dfeat      = (const float*)d_in[1];
    const float* alphaP     = (const float*)d_in[2];
    const float* emb1       = (const float*)d_in[3];
    const float* emb2       = (const float*)d_in[4];
    const float* lin1_w     = (const float*)d_in[5];
    const float* lin1_b     = (const float*)d_in[6];
    const float* lin2_w     = (const float*)d_in[7];
    const float* lin2_b     = (const float*)d_in[8];
    const float* in_proj_w  = (const float*)d_in[9];
    const float* in_proj_b  = (const float*)d_in[10];
    const float* out_proj_w = (const float*)d_in[11];
    const float* out_proj_b = (const float*)d_in[12];
    const float* noise1     = (const float*)d_in[13];
    const float* noise2     = (const float*)d_in[14];
    const float* noise3     = (const float*)d_in[15];
    float* out = (float*)d_out;

    const size_t NN  = NN_;               // 640000
    const size_t BNN = (size_t)BB * NN;   // 5120000

    float* ws  = (float*)d_ws;
    float* v1  = ws;             // BNN   (later reused as a3)
    float* v2  = v1 + BNN;       // BNN
    float* Mb  = v2 + BNN;       // BNN   (M -> adj2 in place, later reused as Kp)
    float* n1  = Mb + BNN;       // 32000
    float* n2  = n1 + NB * DIMM; // 32000
    float* a1d = n2 + NB * DIMM; // NN (dense masked a1)
    float* Qn  = a1d + NN;       // NN
    float* Ob  = Qn + NN;        // NN
    float* a1v = Ob + NN;        // 16000
    int*   a1i = (int*)(a1v + NB * KSEL); // 16000 ints
    float* a3  = v1;             // reuse (v1 dead after M)
    float* Kp  = Mb;             // reuse (adj2 dead after topk2)
    float* a2  = out;            // d_out as scratch (a2, then V)
    float* Vb  = out;

    const float* Wq = in_proj_w;
    const float* Wk = in_proj_w + NN;
    const float* Wv = in_proj_w + 2 * NN;
    const float* bq = in_proj_b;
    const float* bk = in_proj_b + NB;
    const float* bv = in_proj_b + 2 * NB;

    lin_tanh_kernel<<<(NB * DIMM + 255) / 256, 256, 0, stream>>>(emb1, lin1_w, lin1_b, alphaP, n1);
    lin_tanh_kernel<<<(NB * DIMM + 255) / 256, 256, 0, stream>>>(emb2, lin2_w, lin2_b, alphaP, n2);
    adj1_topk_kernel<<<NB, 256, 0, stream>>>(n1, n2, alphaP, noise1, a1d, a1v, a1i);
    vgram_kernel<<<dim3(25, 25, BB), dim3(16, 16), 0, stream>>>(tfeat, v1);
    vgram_kernel<<<dim3(25, 25, BB), dim3(16, 16), 0, stream>>>(dfeat, v2);
    // M = v1 @ v2^T (batched)
    gemm_abt_kernel<<<dim3(13, 13, BB), dim3(16, 16), 0, stream>>>(
        v1, v2, nullptr, Mb, NB, NB, NB, (long)NN, (long)NN, (long)NN, 1, 0);
    // adj2 = M - M^T in place
    antisym_kernel<<<dim3(25, 25, BB), 256, 0, stream>>>(Mb);
    // column top-K of adj2 -> a2 (in d_out), 8 cols/block
    topk2_tile_kernel<<<dim3(NB / 8, BB), 256, 0, stream>>>(Mb, noise2, a2);
    // fused a3 + column top-K, 8 cols/block
    a3_tile_kernel<<<dim3(NB / 8, BB), 256, 0, stream>>>(a2, a1v, a1i, alphaP, noise3, a3);
    gemm_abt_kernel<<<dim3(13, 13, 1), dim3(16, 16), 0, stream>>>(
        a1d, Wq, bq, Qn, NB, NB, NB, 0, 0, 0, 1, 0);
    gemm_abt_kernel<<<dim3(13, 13, BB), dim3(16, 16), 0, stream>>>(
        a2, Wk, bk, Kp, NB, NB, NB, (long)NN, 0, (long)NN, 1, 0);
    gemm_abt_kernel<<<dim3(13, 13, BB), dim3(16, 16), 0, stream>>>(
        a3, Wv, bv, Vb, NB, NB, NB, (long)NN, 0, (long)NN, 1, 0);
    attn_kernel<<<NB, 256, 0, stream>>>(Qn, Kp, Vb, Ob);
    gemm_abt_kernel<<<dim3(13, 13, 1), dim3(16, 16), 0, stream>>>(
        Ob, out_proj_w, out_proj_b, out, NB, NB, NB, 0, 0, 0, BB, (long)NN);
}

// Round 5
// 1023.391 us; speedup vs baseline: 1.7351x; 1.4852x over previous
//
#include <hip/hip_runtime.h>
#include <cmath>

#define NB 800
#define BB 8
#define FF 12
#define DD 32
#define DIMM 40
#define KSEL 20
#define NN_ ((size_t)NB * NB)
#define NSEL (BB * NB * KSEL)

// two-step mul-add with contraction barrier: matches numpy's round(v + round(0.01*n))
__device__ __forceinline__ float score_f32(float v, float n) {
    float p = 0.01f * n;
    asm volatile("" : "+v"(p));
    return v + p;
}

// n = tanh(alpha * (emb @ W^T + b)) : (800,40)
__global__ __launch_bounds__(256) void lin_tanh_kernel(
    const float* __restrict__ emb, const float* __restrict__ W,
    const float* __restrict__ bias, const float* __restrict__ alphaP,
    float* __restrict__ out)
{
    int idx = blockIdx.x * 256 + threadIdx.x;
    if (idx >= NB * DIMM) return;
    int i = idx / DIMM, m = idx - i * DIMM;
    float acc = 0.f;
    #pragma unroll
    for (int d = 0; d < DIMM; ++d) acc += emb[i * DIMM + d] * W[m * DIMM + d];
    acc += bias[m];
    out[idx] = tanhf(alphaP[0] * acc);
}

// Fused adj1 + row top-K, f32 quantized scoring + lowest-index ties.
// Emits only the sorted (idx,val) lists (dense a1 no longer needed).
__global__ __launch_bounds__(256) void adj1_topk_kernel(
    const float* __restrict__ n1, const float* __restrict__ n2,
    const float* __restrict__ alphaP, const float* __restrict__ noise,
    float* __restrict__ a1val, int* __restrict__ a1idx)
{
    int i = blockIdx.x;
    int tid = threadIdx.x;
    __shared__ float vals[NB];
    __shared__ float sc[NB];
    __shared__ float redV[256];
    __shared__ int   redI[256];
    __shared__ int   sel[KSEL];
    __shared__ float n1i[DIMM], n2i[DIMM];
    if (tid < DIMM) { n1i[tid] = n1[i * DIMM + tid]; n2i[tid] = n2[i * DIMM + tid]; }
    __syncthreads();
    float alpha = alphaP[0];
    for (int j = tid; j < NB; j += 256) {
        float s1 = 0.f, s2 = 0.f;
        #pragma unroll
        for (int d = 0; d < DIMM; ++d) {
            s1 += n1i[d] * n2[j * DIMM + d];
            s2 += n2i[d] * n1[j * DIMM + d];
        }
        float t = tanhf(alpha * (s1 - s2));
        float v = t > 0.f ? t : 0.f;
        vals[j] = v;
        sc[j] = score_f32(v, noise[(size_t)i * NB + j]);
    }
    __syncthreads();
    for (int t = 0; t < KSEL; ++t) {
        float bv = -2.0e30f; int bi = NB;
        for (int j = tid; j < NB; j += 256) {
            float s = sc[j];
            if (s > bv || (s == bv && j < bi)) { bv = s; bi = j; }
        }
        redV[tid] = bv; redI[tid] = bi;
        __syncthreads();
        for (int s2 = 128; s2 > 0; s2 >>= 1) {
            if (tid < s2) {
                float ov = redV[tid + s2]; int oi = redI[tid + s2];
                if (ov > redV[tid] || (ov == redV[tid] && oi < redI[tid])) {
                    redV[tid] = ov; redI[tid] = oi;
                }
            }
            __syncthreads();
        }
        if (tid == 0) { sel[t] = redI[0]; sc[redI[0]] = -1.0e30f; }
        __syncthreads();
    }
    if (tid == 0) {
        int tmp[KSEL];
        #pragma unroll
        for (int t = 0; t < KSEL; ++t) tmp[t] = sel[t];
        for (int a = 1; a < KSEL; ++a) {
            int key = tmp[a]; int b = a - 1;
            while (b >= 0 && tmp[b] > key) { tmp[b + 1] = tmp[b]; --b; }
            tmp[b + 1] = key;
        }
        for (int t = 0; t < KSEL; ++t) {
            a1idx[i * KSEL + t] = tmp[t];
            a1val[i * KSEL + t] = vals[tmp[t]];
        }
    }
}

// In-place antisymmetrization: M <- M - M^T (per batch), 32x32 tile pairs.
__global__ __launch_bounds__(256) void antisym_kernel(float* __restrict__ M)
{
    int ti = blockIdx.x, tj = blockIdx.y, b = blockIdx.z;
    if (ti > tj) return;
    float* Mb_ = M + (size_t)b * NN_;
    __shared__ float T1[32][33];
    __shared__ float T2[32][33];
    int tid = threadIdx.x;
    int r = tid >> 3, c4 = (tid & 7) * 4;
    int i0 = ti * 32, j0 = tj * 32;
    float4 x1 = *(const float4*)(Mb_ + (size_t)(i0 + r) * NB + j0 + c4);
    float4 x2 = *(const float4*)(Mb_ + (size_t)(j0 + r) * NB + i0 + c4);
    T1[r][c4] = x1.x; T1[r][c4 + 1] = x1.y; T1[r][c4 + 2] = x1.z; T1[r][c4 + 3] = x1.w;
    T2[r][c4] = x2.x; T2[r][c4 + 1] = x2.y; T2[r][c4 + 2] = x2.z; T2[r][c4 + 3] = x2.w;
    __syncthreads();
    float4 d1;
    d1.x = T1[r][c4 + 0] - T2[c4 + 0][r];
    d1.y = T1[r][c4 + 1] - T2[c4 + 1][r];
    d1.z = T1[r][c4 + 2] - T2[c4 + 2][r];
    d1.w = T1[r][c4 + 3] - T2[c4 + 3][r];
    *(float4*)(Mb_ + (size_t)(i0 + r) * NB + j0 + c4) = d1;
    if (ti != tj) {
        float4 d2;
        d2.x = T2[r][c4 + 0] - T1[c4 + 0][r];
        d2.y = T2[r][c4 + 1] - T1[c4 + 1][r];
        d2.z = T2[r][c4 + 2] - T1[c4 + 2][r];
        d2.w = T2[r][c4 + 3] - T1[c4 + 3][r];
        *(float4*)(Mb_ + (size_t)(j0 + r) * NB + i0 + c4) = d2;
    }
}

// Column top-K of adj2, 8 columns per block. Writes dense masked a2 AND the
// per-column (row,val) selection lists (rank order).
__global__ __launch_bounds__(256) void topk2_tile_kernel(
    const float* __restrict__ adj2, const float* __restrict__ noise,
    float* __restrict__ outp, int* __restrict__ sel2i, float* __restrict__ sel2v)
{
    int j0 = blockIdx.x * 8;
    int b = blockIdx.y;
    int tid = threadIdx.x;
    const float* Ab = adj2 + (size_t)b * NN_;
    const float* Zb = noise + (size_t)b * NN_;
    float* Ob = outp + (size_t)b * NN_;
    __shared__ float sc[NB][9];
    __shared__ float vals[NB][9];
    int c2 = tid & 1, i0 = tid >> 1;
    for (int i = i0; i < NB; i += 128) {
        float4 v  = *(const float4*)(Ab + (size_t)i * NB + j0 + c2 * 4);
        float4 nz = *(const float4*)(Zb + (size_t)i * NB + j0 + c2 * 4);
        int c = c2 * 4;
        vals[i][c + 0] = v.x; vals[i][c + 1] = v.y; vals[i][c + 2] = v.z; vals[i][c + 3] = v.w;
        sc[i][c + 0] = score_f32(v.x, nz.x);
        sc[i][c + 1] = score_f32(v.y, nz.y);
        sc[i][c + 2] = score_f32(v.z, nz.z);
        sc[i][c + 3] = score_f32(v.w, nz.w);
    }
    __syncthreads();
    int g = tid >> 5, l = tid & 31;
    size_t lbase = ((size_t)b * NB + (j0 + g)) * KSEL;
    for (int t = 0; t < KSEL; ++t) {
        float bv = -2.0e30f; int bi = NB;
        for (int i = l; i < NB; i += 32) {
            float s = sc[i][g];
            if (s > bv || (s == bv && i < bi)) { bv = s; bi = i; }
        }
        #pragma unroll
        for (int m = 16; m >= 1; m >>= 1) {
            float ov = __shfl_xor(bv, m, 32);
            int   oi = __shfl_xor(bi, m, 32);
            if (ov > bv || (ov == bv && oi < bi)) { bv = ov; bi = oi; }
        }
        if (l == 0) {
            sc[bi][g] = -1.0e30f;
            sel2i[lbase + t] = bi;
            sel2v[lbase + t] = vals[bi][g];
        }
        __syncthreads();
    }
    for (int i = i0; i < NB; i += 128) {
        int c = c2 * 4;
        float4 o;
        o.x = vals[i][c + 0] * (sc[i][c + 0] == -1.0e30f ? 1.f : 0.f);
        o.y = vals[i][c + 1] * (sc[i][c + 1] == -1.0e30f ? 1.f : 0.f);
        o.z = vals[i][c + 2] * (sc[i][c + 2] == -1.0e30f ? 1.f : 0.f);
        o.w = vals[i][c + 3] * (sc[i][c + 3] == -1.0e30f ? 1.f : 0.f);
        *(float4*)(Ob + (size_t)i * NB + j0 + c2 * 4) = o;
    }
}

// Fused a3 values + column top-K; emits only selection lists (no dense a3).
__global__ __launch_bounds__(256) void a3_tile_kernel(
    const float* __restrict__ a2, const float* __restrict__ a1val,
    const int* __restrict__ a1idx, const float* __restrict__ alphaP,
    const float* __restrict__ noise, int* __restrict__ sel3i, float* __restrict__ sel3v)
{
    int j0 = blockIdx.x * 8;
    int b = blockIdx.y;
    int tid = threadIdx.x;
    const float* a2b = a2 + (size_t)b * NN_;
    const float* Zb  = noise + (size_t)b * NN_;
    __shared__ float sc[NB][9];
    __shared__ float vals[NB][9];
    float alpha = alphaP[0];
    int c2 = tid & 1, i0 = tid >> 1;
    for (int i = i0; i < NB; i += 128) {
        const float* av = a1val + i * KSEL;
        const int*   ai = a1idx + i * KSEL;
        float4 acc = make_float4(0.f, 0.f, 0.f, 0.f);
        #pragma unroll
        for (int t = 0; t < KSEL; ++t) {
            float vt = av[t];
            float4 s = *(const float4*)(a2b + (size_t)ai[t] * NB + j0 + c2 * 4);
            acc.x = fmaf(vt, s.x, acc.x);
            acc.y = fmaf(vt, s.y, acc.y);
            acc.z = fmaf(vt, s.z, acc.z);
            acc.w = fmaf(vt, s.w, acc.w);
        }
        float4 th;
        th.x = tanhf(alpha * acc.x); th.y = tanhf(alpha * acc.y);
        th.z = tanhf(alpha * acc.z); th.w = tanhf(alpha * acc.w);
        th.x = th.x > 0.f ? th.x : 0.f;
        th.y = th.y > 0.f ? th.y : 0.f;
        th.z = th.z > 0.f ? th.z : 0.f;
        th.w = th.w > 0.f ? th.w : 0.f;
        float4 nz = *(const float4*)(Zb + (size_t)i * NB + j0 + c2 * 4);
        int c = c2 * 4;
        vals[i][c + 0] = th.x; vals[i][c + 1] = th.y; vals[i][c + 2] = th.z; vals[i][c + 3] = th.w;
        sc[i][c + 0] = score_f32(th.x, nz.x);
        sc[i][c + 1] = score_f32(th.y, nz.y);
        sc[i][c + 2] = score_f32(th.z, nz.z);
        sc[i][c + 3] = score_f32(th.w, nz.w);
    }
    __syncthreads();
    int g = tid >> 5, l = tid & 31;
    size_t lbase = ((size_t)b * NB + (j0 + g)) * KSEL;
    for (int t = 0; t < KSEL; ++t) {
        float bv = -2.0e30f; int bi = NB;
        for (int i = l; i < NB; i += 32) {
            float s = sc[i][g];
            if (s > bv || (s == bv && i < bi)) { bv = s; bi = i; }
        }
        #pragma unroll
        for (int m = 16; m >= 1; m >>= 1) {
            float ov = __shfl_xor(bv, m, 32);
            int   oi = __shfl_xor(bi, m, 32);
            if (ov > bv || (ov == bv && oi < bi)) { bv = ov; bi = oi; }
        }
        if (l == 0) {
            sc[bi][g] = -1.0e30f;
            sel3i[lbase + t] = bi;
            sel3v[lbase + t] = vals[bi][g];
        }
        __syncthreads();
    }
}

// v[b,i,j] = tanh((sum_f sum_d x[b,f,i,d]*x[b,f,j,d])/F), 64x64 tile, k-major LDS.
__global__ __launch_bounds__(256) void vgram_kernel(
    const float* __restrict__ x, float* __restrict__ v)
{
    int b = blockIdx.z;
    int i0 = blockIdx.y * 64, j0 = blockIdx.x * 64;
    int tid = threadIdx.x;
    int tx = tid & 15, ty = tid >> 4;
    __shared__ __align__(16) float XiT[DD][68];
    __shared__ __align__(16) float XjT[DD][68];
    float acc[4][4] = {};
    for (int f = 0; f < FF; ++f) {
        const float* base = x + ((size_t)b * FF + f) * NB * DD;
        #pragma unroll
        for (int l = 0; l < 2; ++l) {
            int s = tid + l * 256;
            int r = s >> 3, c4 = (s & 7) * 4;
            int ri = i0 + r; if (ri > NB - 1) ri = NB - 1;
            float4 va = *(const float4*)(base + (size_t)ri * DD + c4);
            XiT[c4 + 0][r] = va.x; XiT[c4 + 1][r] = va.y; XiT[c4 + 2][r] = va.z; XiT[c4 + 3][r] = va.w;
            int rj = j0 + r; if (rj > NB - 1) rj = NB - 1;
            float4 vb = *(const float4*)(base + (size_t)rj * DD + c4);
            XjT[c4 + 0][r] = vb.x; XjT[c4 + 1][r] = vb.y; XjT[c4 + 2][r] = vb.z; XjT[c4 + 3][r] = vb.w;
        }
        __syncthreads();
        #pragma unroll 8
        for (int d = 0; d < DD; ++d) {
            float4 a4 = *(const float4*)&XiT[d][ty * 4];
            float4 b4 = *(const float4*)&XjT[d][tx * 4];
            acc[0][0] += a4.x * b4.x; acc[0][1] += a4.x * b4.y; acc[0][2] += a4.x * b4.z; acc[0][3] += a4.x * b4.w;
            acc[1][0] += a4.y * b4.x; acc[1][1] += a4.y * b4.y; acc[1][2] += a4.y * b4.z; acc[1][3] += a4.y * b4.w;
            acc[2][0] += a4.z * b4.x; acc[2][1] += a4.z * b4.y; acc[2][2] += a4.z * b4.z; acc[2][3] += a4.z * b4.w;
            acc[3][0] += a4.w * b4.x; acc[3][1] += a4.w * b4.y; acc[3][2] += a4.w * b4.z; acc[3][3] += a4.w * b4.w;
        }
        __syncthreads();
    }
    size_t basev = (size_t)b * NN_;
    int j = j0 + tx * 4;
    if (j >= NB) return;
    #pragma unroll
    for (int m = 0; m < 4; ++m) {
        int i = i0 + ty * 4 + m;
        if (i >= NB) continue;
        float4 o;
        o.x = tanhf(acc[m][0] / 12.0f);
        o.y = tanhf(acc[m][1] / 12.0f);
        o.z = tanhf(acc[m][2] / 12.0f);
        o.w = tanhf(acc[m][3] / 12.0f);
        *(float4*)(v + basev + (size_t)i * NB + j) = o;
    }
}

// C[b,i,j] = sum_k A[b,i,k]*B[b,j,k] (+bias[j]), replicated nCopies times.
// k-major LDS tiles (BK=32), ds_read_b128 fragment loads, float4 C writes.
__global__ __launch_bounds__(256) void gemm_abt_kernel(
    const float* __restrict__ A, const float* __restrict__ B,
    const float* __restrict__ bias, float* __restrict__ C,
    int M, int Nn, int Kk,
    long aStride, long bStride, long cStride,
    int nCopies, long copyStride)
{
    int bz = blockIdx.z;
    const float* Ab = A + (size_t)bz * aStride;
    const float* Bb = B + (size_t)bz * bStride;
    float* Cb = C + (size_t)bz * cStride;
    int i0 = blockIdx.y * 64, j0 = blockIdx.x * 64;
    int tid = threadIdx.x;
    int tx = tid & 15, ty = tid >> 4;
    __shared__ __align__(16) float AsT[32][68];
    __shared__ __align__(16) float BsT[32][68];
    float acc[4][4] = {};
    for (int kt = 0; kt < Kk; kt += 32) {
        #pragma unroll
        for (int l = 0; l < 2; ++l) {
            int s = tid + l * 256;
            int r = s >> 3, c4 = (s & 7) * 4;
            int ai = i0 + r;
            float4 va = make_float4(0.f, 0.f, 0.f, 0.f);
            if (ai < M) va = *(const float4*)(Ab + (size_t)ai * Kk + kt + c4);
            AsT[c4 + 0][r] = va.x; AsT[c4 + 1][r] = va.y; AsT[c4 + 2][r] = va.z; AsT[c4 + 3][r] = va.w;
            int bj = j0 + r;
            float4 vb = make_float4(0.f, 0.f, 0.f, 0.f);
            if (bj < Nn) vb = *(const float4*)(Bb + (size_t)bj * Kk + kt + c4);
            BsT[c4 + 0][r] = vb.x; BsT[c4 + 1][r] = vb.y; BsT[c4 + 2][r] = vb.z; BsT[c4 + 3][r] = vb.w;
        }
        __syncthreads();
        #pragma unroll 8
        for (int kk = 0; kk < 32; ++kk) {
            float4 a4 = *(const float4*)&AsT[kk][ty * 4];
            float4 b4 = *(const float4*)&BsT[kk][tx * 4];
            acc[0][0] += a4.x * b4.x; acc[0][1] += a4.x * b4.y; acc[0][2] += a4.x * b4.z; acc[0][3] += a4.x * b4.w;
            acc[1][0] += a4.y * b4.x; acc[1][1] += a4.y * b4.y; acc[1][2] += a4.y * b4.z; acc[1][3] += a4.y * b4.w;
            acc[2][0] += a4.z * b4.x; acc[2][1] += a4.z * b4.y; acc[2][2] += a4.z * b4.z; acc[2][3] += a4.z * b4.w;
            acc[3][0] += a4.w * b4.x; acc[3][1] += a4.w * b4.y; acc[3][2] += a4.w * b4.z; acc[3][3] += a4.w * b4.w;
        }
        __syncthreads();
    }
    int j = j0 + tx * 4;
    if (j >= Nn) return;
    #pragma unroll
    for (int m = 0; m < 4; ++m) {
        int i = i0 + ty * 4 + m;
        if (i >= M) continue;
        float4 o;
        o.x = acc[m][0] + (bias ? bias[j + 0] : 0.f);
        o.y = acc[m][1] + (bias ? bias[j + 1] : 0.f);
        o.z = acc[m][2] + (bias ? bias[j + 2] : 0.f);
        o.w = acc[m][3] + (bias ? bias[j + 3] : 0.f);
        for (int c = 0; c < nCopies; ++c)
            *(float4*)(Cb + (size_t)c * copyStride + (size_t)i * Nn + j) = o;
    }
}

// Wt[z][j][e] = W[z][e][j] for z=0(Wq),1(Wk)
__global__ __launch_bounds__(256) void transpose_w_kernel(
    const float* __restrict__ W, float* __restrict__ Wt)
{
    int z = blockIdx.z;
    const float* in = W + (size_t)z * NN_;
    float* outp = Wt + (size_t)z * NN_;
    __shared__ float T[32][33];
    int e0 = blockIdx.y * 32, j0 = blockIdx.x * 32;
    int tid = threadIdx.x;
    int r = tid >> 3, c4 = (tid & 7) * 4;
    float4 v = *(const float4*)(in + (size_t)(e0 + r) * NB + j0 + c4);
    T[r][c4 + 0] = v.x; T[r][c4 + 1] = v.y; T[r][c4 + 2] = v.z; T[r][c4 + 3] = v.w;
    __syncthreads();
    float4 o;
    o.x = T[c4 + 0][r]; o.y = T[c4 + 1][r]; o.z = T[c4 + 2][r]; o.w = T[c4 + 3][r];
    *(float4*)(outp + (size_t)(j0 + r) * NB + e0 + c4) = o;
}

// Qn[i,:] = sum_t a1val[i,t]*Wqt[a1idx[i,t],:] + bq (a1 is exactly 20-sparse/row)
__global__ __launch_bounds__(256) void qn_sparse_kernel(
    const float* __restrict__ a1v, const int* __restrict__ a1i,
    const float* __restrict__ Wqt, const float* __restrict__ bq,
    float* __restrict__ Qn)
{
    int i = blockIdx.x;
    int tid = threadIdx.x;
    __shared__ float sval[KSEL];
    __shared__ int   sidx[KSEL];
    if (tid < KSEL) { sval[tid] = a1v[i * KSEL + tid]; sidx[tid] = a1i[i * KSEL + tid]; }
    __syncthreads();
    for (int e = tid; e < NB; e += 256) {
        float acc = 0.f;
        #pragma unroll
        for (int t = 0; t < KSEL; ++t)
            acc = fmaf(sval[t], Wqt[(size_t)sidx[t] * NB + e], acc);
        Qn[(size_t)i * NB + e] = acc + bq[e];
    }
}

// scores[n,b] += a2val * g[n,j] over a2's selected entries
__global__ __launch_bounds__(256) void scatter_scores_kernel(
    const int* __restrict__ sel2i, const float* __restrict__ sel2v,
    const float* __restrict__ g, float* __restrict__ scores)
{
    int t = blockIdx.x * 256 + threadIdx.x;
    if (t >= NSEL) return;
    int j = (t / KSEL) % NB;
    int b = t / (KSEL * NB);
    int n = sel2i[t];
    float val = sel2v[t];
    atomicAdd(scores + (size_t)n * BB + b, val * g[(size_t)n * NB + j]);
}

// w[n,:] = softmax(scores[n,:]/sqrt(800))
__global__ __launch_bounds__(256) void softmax_w_kernel(
    const float* __restrict__ scores, float* __restrict__ w)
{
    int n = blockIdx.x * 256 + threadIdx.x;
    if (n >= NB) return;
    float s[BB];
    float mx = -INFINITY;
    for (int k = 0; k < BB; ++k) {
        s[k] = scores[(size_t)n * BB + k] / sqrtf(800.0f);
        if (s[k] > mx) mx = s[k];
    }
    float sum = 0.f;
    for (int k = 0; k < BB; ++k) { s[k] = expf(s[k] - mx); sum += s[k]; }
    for (int k = 0; k < BB; ++k) w[(size_t)n * BB + k] = s[k] / sum;
}

// u[n,j] += w[n,b] * a3val over a3's selected entries
__global__ __launch_bounds__(256) void scatter_u_kernel(
    const int* __restrict__ sel3i, const float* __restrict__ sel3v,
    const float* __restrict__ w, float* __restrict__ u)
{
    int t = blockIdx.x * 256 + threadIdx.x;
    if (t >= NSEL) return;
    int j = (t / KSEL) % NB;
    int b = t / (KSEL * NB);
    int n = sel3i[t];
    float val = sel3v[t];
    atomicAdd(u + (size_t)n * NB + j, w[(size_t)n * BB + b] * val);
}

extern "C" void kernel_launch(void* const* d_in, const int* in_sizes, int n_in,
                              void* d_out, int out_size, void* d_ws, size_t ws_size,
                              hipStream_t stream)
{
    const float* tfeat      = (const float*)d_in[0];
    const float* dfeat      = (const float*)d_in[1];
    const float* alphaP     = (const float*)d_in[2];
    const float* emb1       = (const float*)d_in[3];
    const float* emb2       = (const float*)d_in[4];
    const float* lin1_w     = (const float*)d_in[5];
    const float* lin1_b     = (const float*)d_in[6];
    const float* lin2_w     = (const float*)d_in[7];
    const float* lin2_b     = (const float*)d_in[8];
    const float* in_proj_w  = (const float*)d_in[9];
    const float* out_proj_w = (const float*)d_in[11];
    const float* out_proj_b = (const float*)d_in[12];
    const float* noise1     = (const float*)d_in[13];
    const float* noise2     = (const float*)d_in[14];
    const float* noise3     = (const float*)d_in[15];
    const float* in_proj_b  = (const float*)d_in[10];
    float* out = (float*)d_out;

    const size_t NN  = NN_;               // 640000
    const size_t BNN = (size_t)BB * NN;   // 5120000

    float* ws  = (float*)d_ws;
    float* v1  = ws;              // BNN (later: u)
    float* v2  = v1 + BNN;        // BNN (later: g)
    float* Mb  = v2 + BNN;        // BNN (later: Wqt/Wkt)
    float* n1  = Mb + BNN;        // 32000
    float* n2  = n1 + NB * DIMM;  // 32000
    float* Qn  = n2 + NB * DIMM;  // NN
    float* Ob  = Qn + NN;         // NN
    float* a1v = Ob + NN;         // 16000
    int*   a1i = (int*)(a1v + NB * KSEL);       // 16000
    float* sel2v = (float*)(a1i + NB * KSEL);   // 128000
    int*   sel2i = (int*)(sel2v + NSEL);        // 128000
    float* sel3v = (float*)(sel2i + NSEL);      // 128000
    int*   sel3i = (int*)(sel3v + NSEL);        // 128000
    float* scores = (float*)(sel3i + NSEL);     // 6400
    float* wgt    = scores + NB * BB;           // 6400
    float* u  = v1;
    float* g  = v2;
    float* Wt = Mb;               // Wqt = Wt, Wkt = Wt + NN
    float* a2 = out;              // d_out as scratch until final gemm

    const float* bq = in_proj_b;

    lin_tanh_kernel<<<(NB * DIMM + 255) / 256, 256, 0, stream>>>(emb1, lin1_w, lin1_b, alphaP, n1);
    lin_tanh_kernel<<<(NB * DIMM + 255) / 256, 256, 0, stream>>>(emb2, lin2_w, lin2_b, alphaP, n2);
    adj1_topk_kernel<<<NB, 256, 0, stream>>>(n1, n2, alphaP, noise1, a1v, a1i);
    vgram_kernel<<<dim3(13, 13, BB), 256, 0, stream>>>(tfeat, v1);
    vgram_kernel<<<dim3(13, 13, BB), 256, 0, stream>>>(dfeat, v2);
    // M = v1 @ v2^T (batched)
    gemm_abt_kernel<<<dim3(13, 13, BB), 256, 0, stream>>>(
        v1, v2, nullptr, Mb, NB, NB, NB, (long)NN, (long)NN, (long)NN, 1, 0);
    antisym_kernel<<<dim3(25, 25, BB), 256, 0, stream>>>(Mb);
    topk2_tile_kernel<<<dim3(NB / 8, BB), 256, 0, stream>>>(Mb, noise2, a2, sel2i, sel2v);
    a3_tile_kernel<<<dim3(NB / 8, BB), 256, 0, stream>>>(a2, a1v, a1i, alphaP, noise3, sel3i, sel3v);
    // Wqt, Wkt (Mb dead after topk2)
    transpose_w_kernel<<<dim3(25, 25, 2), 256, 0, stream>>>(in_proj_w, Wt);
    qn_sparse_kernel<<<NB, 256, 0, stream>>>(a1v, a1i, Wt, bq, Qn);
    // g = Qn @ Wk  (= gemm_abt(Qn, Wkt))
    gemm_abt_kernel<<<dim3(13, 13, 1), 256, 0, stream>>>(
        Qn, Wt + NN, nullptr, g, NB, NB, NB, 0, 0, 0, 1, 0);
    hipMemsetAsync(scores, 0, NB * BB * sizeof(float), stream);
    scatter_scores_kernel<<<NSEL / 256, 256, 0, stream>>>(sel2i, sel2v, g, scores);
    softmax_w_kernel<<<(NB + 255) / 256, 256, 0, stream>>>(scores, wgt);
    hipMemsetAsync(u, 0, NN * sizeof(float), stream);
    scatter_u_kernel<<<NSEL / 256, 256, 0, stream>>>(sel3i, sel3v, wgt, u);
    // O = u @ Wv^T + bv
    gemm_abt_kernel<<<dim3(13, 13, 1), 256, 0, stream>>>(
        u, in_proj_w + 2 * NN, in_proj_b + 2 * NB, Ob, NB, NB, NB, 0, 0, 0, 1, 0);
    // out = O @ Wout^T + bout, broadcast to 8 copies
    gemm_abt_kernel<<<dim3(13, 13, 1), 256, 0, stream>>>(
        Ob, out_proj_w, out_proj_b, out, NB, NB, NB, 0, 0, 0, BB, (long)NN);
}

// Round 6
// 913.862 us; speedup vs baseline: 1.9431x; 1.1199x over previous
//
#include <hip/hip_runtime.h>
#include <cmath>

#define NB 800
#define BB 8
#define FF 12
#define DD 32
#define DIMM 40
#define KSEL 20
#define NN_ ((size_t)NB * NB)
#define NSEL (BB * NB * KSEL)

// two-step mul-add with contraction barrier: matches numpy's round(v + round(0.01*n))
__device__ __forceinline__ float score_f32(float v, float n) {
    float p = 0.01f * n;
    asm volatile("" : "+v"(p));
    return v + p;
}

// n = tanh(alpha * (emb @ W^T + b)) : (800,40)
__global__ __launch_bounds__(256) void lin_tanh_kernel(
    const float* __restrict__ emb, const float* __restrict__ W,
    const float* __restrict__ bias, const float* __restrict__ alphaP,
    float* __restrict__ out)
{
    int idx = blockIdx.x * 256 + threadIdx.x;
    if (idx >= NB * DIMM) return;
    int i = idx / DIMM, m = idx - i * DIMM;
    float acc = 0.f;
    #pragma unroll
    for (int d = 0; d < DIMM; ++d) acc += emb[i * DIMM + d] * W[m * DIMM + d];
    acc += bias[m];
    out[idx] = tanhf(alphaP[0] * acc);
}

// Fused adj1 + row top-K, f32 quantized scoring + lowest-index ties.
__global__ __launch_bounds__(256) void adj1_topk_kernel(
    const float* __restrict__ n1, const float* __restrict__ n2,
    const float* __restrict__ alphaP, const float* __restrict__ noise,
    float* __restrict__ a1val, int* __restrict__ a1idx)
{
    int i = blockIdx.x;
    int tid = threadIdx.x;
    __shared__ float vals[NB];
    __shared__ float sc[NB];
    __shared__ float redV[256];
    __shared__ int   redI[256];
    __shared__ int   sel[KSEL];
    __shared__ float n1i[DIMM], n2i[DIMM];
    if (tid < DIMM) { n1i[tid] = n1[i * DIMM + tid]; n2i[tid] = n2[i * DIMM + tid]; }
    __syncthreads();
    float alpha = alphaP[0];
    for (int j = tid; j < NB; j += 256) {
        float s1 = 0.f, s2 = 0.f;
        #pragma unroll
        for (int d = 0; d < DIMM; ++d) {
            s1 += n1i[d] * n2[j * DIMM + d];
            s2 += n2i[d] * n1[j * DIMM + d];
        }
        float t = tanhf(alpha * (s1 - s2));
        float v = t > 0.f ? t : 0.f;
        vals[j] = v;
        sc[j] = score_f32(v, noise[(size_t)i * NB + j]);
    }
    __syncthreads();
    for (int t = 0; t < KSEL; ++t) {
        float bv = -2.0e30f; int bi = NB;
        for (int j = tid; j < NB; j += 256) {
            float s = sc[j];
            if (s > bv || (s == bv && j < bi)) { bv = s; bi = j; }
        }
        redV[tid] = bv; redI[tid] = bi;
        __syncthreads();
        for (int s2 = 128; s2 > 0; s2 >>= 1) {
            if (tid < s2) {
                float ov = redV[tid + s2]; int oi = redI[tid + s2];
                if (ov > redV[tid] || (ov == redV[tid] && oi < redI[tid])) {
                    redV[tid] = ov; redI[tid] = oi;
                }
            }
            __syncthreads();
        }
        if (tid == 0) { sel[t] = redI[0]; sc[redI[0]] = -1.0e30f; }
        __syncthreads();
    }
    if (tid == 0) {
        int tmp[KSEL];
        #pragma unroll
        for (int t = 0; t < KSEL; ++t) tmp[t] = sel[t];
        for (int a = 1; a < KSEL; ++a) {
            int key = tmp[a]; int b = a - 1;
            while (b >= 0 && tmp[b] > key) { tmp[b + 1] = tmp[b]; --b; }
            tmp[b + 1] = key;
        }
        for (int t = 0; t < KSEL; ++t) {
            a1idx[i * KSEL + t] = tmp[t];
            a1val[i * KSEL + t] = vals[tmp[t]];
        }
    }
}

// In-place antisymmetrization: M <- M - M^T (per batch), 32x32 tile pairs.
__global__ __launch_bounds__(256) void antisym_kernel(float* __restrict__ M)
{
    int ti = blockIdx.x, tj = blockIdx.y, b = blockIdx.z;
    if (ti > tj) return;
    float* Mb_ = M + (size_t)b * NN_;
    __shared__ float T1[32][33];
    __shared__ float T2[32][33];
    int tid = threadIdx.x;
    int r = tid >> 3, c4 = (tid & 7) * 4;
    int i0 = ti * 32, j0 = tj * 32;
    float4 x1 = *(const float4*)(Mb_ + (size_t)(i0 + r) * NB + j0 + c4);
    float4 x2 = *(const float4*)(Mb_ + (size_t)(j0 + r) * NB + i0 + c4);
    T1[r][c4] = x1.x; T1[r][c4 + 1] = x1.y; T1[r][c4 + 2] = x1.z; T1[r][c4 + 3] = x1.w;
    T2[r][c4] = x2.x; T2[r][c4 + 1] = x2.y; T2[r][c4 + 2] = x2.z; T2[r][c4 + 3] = x2.w;
    __syncthreads();
    float4 d1;
    d1.x = T1[r][c4 + 0] - T2[c4 + 0][r];
    d1.y = T1[r][c4 + 1] - T2[c4 + 1][r];
    d1.z = T1[r][c4 + 2] - T2[c4 + 2][r];
    d1.w = T1[r][c4 + 3] - T2[c4 + 3][r];
    *(float4*)(Mb_ + (size_t)(i0 + r) * NB + j0 + c4) = d1;
    if (ti != tj) {
        float4 d2;
        d2.x = T2[r][c4 + 0] - T1[c4 + 0][r];
        d2.y = T2[r][c4 + 1] - T1[c4 + 1][r];
        d2.z = T2[r][c4 + 2] - T1[c4 + 2][r];
        d2.w = T2[r][c4 + 3] - T1[c4 + 3][r];
        *(float4*)(Mb_ + (size_t)(j0 + r) * NB + i0 + c4) = d2;
    }
}

// Column top-K of adj2, 4 columns/block, XCD-pinned (b = bid&7). Per-wave scan
// (64-lane groups, no per-round barrier), values in registers.
__global__ __launch_bounds__(256) void topk2_tile_kernel(
    const float* __restrict__ adj2, const float* __restrict__ noise,
    float* __restrict__ outp, int* __restrict__ sel2i, float* __restrict__ sel2v)
{
    int bid = blockIdx.x;
    int b = bid & 7;
    int j0 = (bid >> 3) * 4;
    int tid = threadIdx.x;
    const float* Ab = adj2 + (size_t)b * NN_;
    const float* Zb = noise + (size_t)b * NN_;
    float* Ob = outp + (size_t)b * NN_;
    __shared__ float sc[NB][5];
    __shared__ int selIdx[4][KSEL];
    float4 myval[4];
    #pragma unroll
    for (int k = 0; k < 4; ++k) {
        int i = tid + k * 256;
        if (i < NB) {
            float4 v  = *(const float4*)(Ab + (size_t)i * NB + j0);
            float4 nz = *(const float4*)(Zb + (size_t)i * NB + j0);
            myval[k] = v;
            sc[i][0] = score_f32(v.x, nz.x);
            sc[i][1] = score_f32(v.y, nz.y);
            sc[i][2] = score_f32(v.z, nz.z);
            sc[i][3] = score_f32(v.w, nz.w);
        }
    }
    __syncthreads();
    int g = tid >> 6, l = tid & 63;
    size_t lbase = ((size_t)b * NB + (j0 + g)) * KSEL;
    for (int t = 0; t < KSEL; ++t) {
        float bv = -2.0e30f; int bi = NB;
        for (int i = l; i < NB; i += 64) {
            float s = sc[i][g];
            if (s > bv || (s == bv && i < bi)) { bv = s; bi = i; }
        }
        #pragma unroll
        for (int m = 32; m >= 1; m >>= 1) {
            float ov = __shfl_xor(bv, m, 64);
            int   oi = __shfl_xor(bi, m, 64);
            if (ov > bv || (ov == bv && oi < bi)) { bv = ov; bi = oi; }
        }
        if (l == 0) {
            sc[bi][g] = -1.0e30f;   // tombstone = selection mark (intra-wave visible)
            selIdx[g][t] = bi;
            sel2i[lbase + t] = bi;
        }
    }
    __syncthreads();
    #pragma unroll
    for (int k = 0; k < 4; ++k) {
        int i = tid + k * 256;
        if (i >= NB) continue;
        float vv[4] = {myval[k].x, myval[k].y, myval[k].z, myval[k].w};
        float o4[4];
        #pragma unroll
        for (int c = 0; c < 4; ++c) {
            bool seld = (sc[i][c] == -1.0e30f);
            o4[c] = seld ? vv[c] : 0.f;
            if (seld) {
                int rk = 0;
                for (int t = 0; t < KSEL; ++t) if (selIdx[c][t] == i) rk = t;
                sel2v[((size_t)b * NB + (j0 + c)) * KSEL + rk] = vv[c];
            }
        }
        *(float4*)(Ob + (size_t)i * NB + j0) = make_float4(o4[0], o4[1], o4[2], o4[3]);
    }
}

// Fused a3 (sparse a1 gather-GEMM, fmaf ascending-t) + column top-K,
// 4 columns/block, XCD-pinned. Emits only selection lists.
__global__ __launch_bounds__(256) void a3_tile_kernel(
    const float* __restrict__ a2, const float* __restrict__ a1val,
    const int* __restrict__ a1idx, const float* __restrict__ alphaP,
    const float* __restrict__ noise, int* __restrict__ sel3i, float* __restrict__ sel3v)
{
    int bid = blockIdx.x;
    int b = bid & 7;
    int j0 = (bid >> 3) * 4;
    int tid = threadIdx.x;
    const float* a2b = a2 + (size_t)b * NN_;
    const float* Zb  = noise + (size_t)b * NN_;
    __shared__ float sc[NB][5];
    __shared__ int selIdx[4][KSEL];
    float alpha = alphaP[0];
    float4 myval[4];
    #pragma unroll
    for (int k = 0; k < 4; ++k) {
        int i = tid + k * 256;
        if (i < NB) {
            const float* av = a1val + i * KSEL;
            const int*   ai = a1idx + i * KSEL;
            float4 acc = make_float4(0.f, 0.f, 0.f, 0.f);
            #pragma unroll
            for (int t = 0; t < KSEL; ++t) {
                float vt = av[t];
                float4 s = *(const float4*)(a2b + (size_t)ai[t] * NB + j0);
                acc.x = fmaf(vt, s.x, acc.x);
                acc.y = fmaf(vt, s.y, acc.y);
                acc.z = fmaf(vt, s.z, acc.z);
                acc.w = fmaf(vt, s.w, acc.w);
            }
            float4 th;
            th.x = tanhf(alpha * acc.x); th.y = tanhf(alpha * acc.y);
            th.z = tanhf(alpha * acc.z); th.w = tanhf(alpha * acc.w);
            th.x = th.x > 0.f ? th.x : 0.f;
            th.y = th.y > 0.f ? th.y : 0.f;
            th.z = th.z > 0.f ? th.z : 0.f;
            th.w = th.w > 0.f ? th.w : 0.f;
            float4 nz = *(const float4*)(Zb + (size_t)i * NB + j0);
            myval[k] = th;
            sc[i][0] = score_f32(th.x, nz.x);
            sc[i][1] = score_f32(th.y, nz.y);
            sc[i][2] = score_f32(th.z, nz.z);
            sc[i][3] = score_f32(th.w, nz.w);
        }
    }
    __syncthreads();
    int g = tid >> 6, l = tid & 63;
    size_t lbase = ((size_t)b * NB + (j0 + g)) * KSEL;
    for (int t = 0; t < KSEL; ++t) {
        float bv = -2.0e30f; int bi = NB;
        for (int i = l; i < NB; i += 64) {
            float s = sc[i][g];
            if (s > bv || (s == bv && i < bi)) { bv = s; bi = i; }
        }
        #pragma unroll
        for (int m = 32; m >= 1; m >>= 1) {
            float ov = __shfl_xor(bv, m, 64);
            int   oi = __shfl_xor(bi, m, 64);
            if (ov > bv || (ov == bv && oi < bi)) { bv = ov; bi = oi; }
        }
        if (l == 0) {
            sc[bi][g] = -1.0e30f;
            selIdx[g][t] = bi;
            sel3i[lbase + t] = bi;
        }
    }
    __syncthreads();
    #pragma unroll
    for (int k = 0; k < 4; ++k) {
        int i = tid + k * 256;
        if (i >= NB) continue;
        float vv[4] = {myval[k].x, myval[k].y, myval[k].z, myval[k].w};
        #pragma unroll
        for (int c = 0; c < 4; ++c) {
            if (sc[i][c] == -1.0e30f) {
                int rk = 0;
                for (int t = 0; t < KSEL; ++t) if (selIdx[c][t] == i) rk = t;
                sel3v[((size_t)b * NB + (j0 + c)) * KSEL + rk] = vv[c];
            }
        }
    }
}

// v[b,i,j] = tanh((sum_f sum_d x[b,f,i,d]*x[b,f,j,d])/F), 64x64 tile, k-major
// LDS, XCD-pinned 1-D grid.
__global__ __launch_bounds__(256) void vgram_kernel(
    const float* __restrict__ x, float* __restrict__ v)
{
    int bid = blockIdx.x;
    int b = bid & 7;
    int t_ = bid >> 3;
    int i0 = (t_ / 13) * 64, j0 = (t_ % 13) * 64;
    int tid = threadIdx.x;
    int tx = tid & 15, ty = tid >> 4;
    __shared__ __align__(16) float XiT[DD][68];
    __shared__ __align__(16) float XjT[DD][68];
    float acc[4][4] = {};
    for (int f = 0; f < FF; ++f) {
        const float* base = x + ((size_t)b * FF + f) * NB * DD;
        #pragma unroll
        for (int l = 0; l < 2; ++l) {
            int s = tid + l * 256;
            int r = s >> 3, c4 = (s & 7) * 4;
            int ri = i0 + r; if (ri > NB - 1) ri = NB - 1;
            float4 va = *(const float4*)(base + (size_t)ri * DD + c4);
            XiT[c4 + 0][r] = va.x; XiT[c4 + 1][r] = va.y; XiT[c4 + 2][r] = va.z; XiT[c4 + 3][r] = va.w;
            int rj = j0 + r; if (rj > NB - 1) rj = NB - 1;
            float4 vb = *(const float4*)(base + (size_t)rj * DD + c4);
            XjT[c4 + 0][r] = vb.x; XjT[c4 + 1][r] = vb.y; XjT[c4 + 2][r] = vb.z; XjT[c4 + 3][r] = vb.w;
        }
        __syncthreads();
        #pragma unroll 8
        for (int d = 0; d < DD; ++d) {
            float4 a4 = *(const float4*)&XiT[d][ty * 4];
            float4 b4 = *(const float4*)&XjT[d][tx * 4];
            acc[0][0] += a4.x * b4.x; acc[0][1] += a4.x * b4.y; acc[0][2] += a4.x * b4.z; acc[0][3] += a4.x * b4.w;
            acc[1][0] += a4.y * b4.x; acc[1][1] += a4.y * b4.y; acc[1][2] += a4.y * b4.z; acc[1][3] += a4.y * b4.w;
            acc[2][0] += a4.z * b4.x; acc[2][1] += a4.z * b4.y; acc[2][2] += a4.z * b4.z; acc[2][3] += a4.z * b4.w;
            acc[3][0] += a4.w * b4.x; acc[3][1] += a4.w * b4.y; acc[3][2] += a4.w * b4.z; acc[3][3] += a4.w * b4.w;
        }
        __syncthreads();
    }
    size_t basev = (size_t)b * NN_;
    int j = j0 + tx * 4;
    if (j >= NB) return;
    #pragma unroll
    for (int m = 0; m < 4; ++m) {
        int i = i0 + ty * 4 + m;
        if (i >= NB) continue;
        float4 o;
        o.x = tanhf(acc[m][0] / 12.0f);
        o.y = tanhf(acc[m][1] / 12.0f);
        o.z = tanhf(acc[m][2] / 12.0f);
        o.w = tanhf(acc[m][3] / 12.0f);
        *(float4*)(v + basev + (size_t)i * NB + j) = o;
    }
}

// C[b,i,j] = sum_k A[b,i,k]*B[b,j,k] (+bias[j]), replicated nCopies times.
// k-major LDS tiles (BK=32), XCD-pinned 1-D grid decode (bz = bid % nBatch).
__global__ __launch_bounds__(256) void gemm_abt_kernel(
    const float* __restrict__ A, const float* __restrict__ B,
    const float* __restrict__ bias, float* __restrict__ C,
    int M, int Nn, int Kk,
    long aStride, long bStride, long cStride,
    int nCopies, long copyStride, int tilesX, int nBatch)
{
    int bid = blockIdx.x;
    int bz = bid % nBatch;
    int t_ = bid / nBatch;
    int j0 = (t_ % tilesX) * 64;
    int i0 = (t_ / tilesX) * 64;
    const float* Ab = A + (size_t)bz * aStride;
    const float* Bb = B + (size_t)bz * bStride;
    float* Cb = C + (size_t)bz * cStride;
    int tid = threadIdx.x;
    int tx = tid & 15, ty = tid >> 4;
    __shared__ __align__(16) float AsT[32][68];
    __shared__ __align__(16) float BsT[32][68];
    float acc[4][4] = {};
    for (int kt = 0; kt < Kk; kt += 32) {
        #pragma unroll
        for (int l = 0; l < 2; ++l) {
            int s = tid + l * 256;
            int r = s >> 3, c4 = (s & 7) * 4;
            int ai = i0 + r;
            float4 va = make_float4(0.f, 0.f, 0.f, 0.f);
            if (ai < M) va = *(const float4*)(Ab + (size_t)ai * Kk + kt + c4);
            AsT[c4 + 0][r] = va.x; AsT[c4 + 1][r] = va.y; AsT[c4 + 2][r] = va.z; AsT[c4 + 3][r] = va.w;
            int bj = j0 + r;
            float4 vb = make_float4(0.f, 0.f, 0.f, 0.f);
            if (bj < Nn) vb = *(const float4*)(Bb + (size_t)bj * Kk + kt + c4);
            BsT[c4 + 0][r] = vb.x; BsT[c4 + 1][r] = vb.y; BsT[c4 + 2][r] = vb.z; BsT[c4 + 3][r] = vb.w;
        }
        __syncthreads();
        #pragma unroll 8
        for (int kk = 0; kk < 32; ++kk) {
            float4 a4 = *(const float4*)&AsT[kk][ty * 4];
            float4 b4 = *(const float4*)&BsT[kk][tx * 4];
            acc[0][0] += a4.x * b4.x; acc[0][1] += a4.x * b4.y; acc[0][2] += a4.x * b4.z; acc[0][3] += a4.x * b4.w;
            acc[1][0] += a4.y * b4.x; acc[1][1] += a4.y * b4.y; acc[1][2] += a4.y * b4.z; acc[1][3] += a4.y * b4.w;
            acc[2][0] += a4.z * b4.x; acc[2][1] += a4.z * b4.y; acc[2][2] += a4.z * b4.z; acc[2][3] += a4.z * b4.w;
            acc[3][0] += a4.w * b4.x; acc[3][1] += a4.w * b4.y; acc[3][2] += a4.w * b4.z; acc[3][3] += a4.w * b4.w;
        }
        __syncthreads();
    }
    int j = j0 + tx * 4;
    if (j >= Nn) return;
    #pragma unroll
    for (int m = 0; m < 4; ++m) {
        int i = i0 + ty * 4 + m;
        if (i >= M) continue;
        float4 o;
        o.x = acc[m][0] + (bias ? bias[j + 0] : 0.f);
        o.y = acc[m][1] + (bias ? bias[j + 1] : 0.f);
        o.z = acc[m][2] + (bias ? bias[j + 2] : 0.f);
        o.w = acc[m][3] + (bias ? bias[j + 3] : 0.f);
        for (int c = 0; c < nCopies; ++c)
            *(float4*)(Cb + (size_t)c * copyStride + (size_t)i * Nn + j) = o;
    }
}

// Wt[z][j][e] = W[z][e][j] for z=0(Wq),1(Wk)
__global__ __launch_bounds__(256) void transpose_w_kernel(
    const float* __restrict__ W, float* __restrict__ Wt)
{
    int z = blockIdx.z;
    const float* in = W + (size_t)z * NN_;
    float* outp = Wt + (size_t)z * NN_;
    __shared__ float T[32][33];
    int e0 = blockIdx.y * 32, j0 = blockIdx.x * 32;
    int tid = threadIdx.x;
    int r = tid >> 3, c4 = (tid & 7) * 4;
    float4 v = *(const float4*)(in + (size_t)(e0 + r) * NB + j0 + c4);
    T[r][c4 + 0] = v.x; T[r][c4 + 1] = v.y; T[r][c4 + 2] = v.z; T[r][c4 + 3] = v.w;
    __syncthreads();
    float4 o;
    o.x = T[c4 + 0][r]; o.y = T[c4 + 1][r]; o.z = T[c4 + 2][r]; o.w = T[c4 + 3][r];
    *(float4*)(outp + (size_t)(j0 + r) * NB + e0 + c4) = o;
}

// Qn[i,:] = sum_t a1val[i,t]*Wqt[a1idx[i,t],:] + bq
__global__ __launch_bounds__(256) void qn_sparse_kernel(
    const float* __restrict__ a1v, const int* __restrict__ a1i,
    const float* __restrict__ Wqt, const float* __restrict__ bq,
    float* __restrict__ Qn)
{
    int i = blockIdx.x;
    int tid = threadIdx.x;
    __shared__ float sval[KSEL];
    __shared__ int   sidx[KSEL];
    if (tid < KSEL) { sval[tid] = a1v[i * KSEL + tid]; sidx[tid] = a1i[i * KSEL + tid]; }
    __syncthreads();
    for (int e = tid; e < NB; e += 256) {
        float acc = 0.f;
        #pragma unroll
        for (int t = 0; t < KSEL; ++t)
            acc = fmaf(sval[t], Wqt[(size_t)sidx[t] * NB + e], acc);
        Qn[(size_t)i * NB + e] = acc + bq[e];
    }
}

// scores[n,b] += a2val * g[n,j] over a2's selected entries
__global__ __launch_bounds__(256) void scatter_scores_kernel(
    const int* __restrict__ sel2i, const float* __restrict__ sel2v,
    const float* __restrict__ g, float* __restrict__ scores)
{
    int t = blockIdx.x * 256 + threadIdx.x;
    if (t >= NSEL) return;
    int j = (t / KSEL) % NB;
    int b = t / (KSEL * NB);
    int n = sel2i[t];
    float val = sel2v[t];
    atomicAdd(scores + (size_t)n * BB + b, val * g[(size_t)n * NB + j]);
}

// w[n,:] = softmax(scores[n,:]/sqrt(800))
__global__ __launch_bounds__(256) void softmax_w_kernel(
    const float* __restrict__ scores, float* __restrict__ w)
{
    int n = blockIdx.x * 256 + threadIdx.x;
    if (n >= NB) return;
    float s[BB];
    float mx = -INFINITY;
    for (int k = 0; k < BB; ++k) {
        s[k] = scores[(size_t)n * BB + k] / sqrtf(800.0f);
        if (s[k] > mx) mx = s[k];
    }
    float sum = 0.f;
    for (int k = 0; k < BB; ++k) { s[k] = expf(s[k] - mx); sum += s[k]; }
    for (int k = 0; k < BB; ++k) w[(size_t)n * BB + k] = s[k] / sum;
}

// u[n,j] += w[n,b] * a3val over a3's selected entries
__global__ __launch_bounds__(256) void scatter_u_kernel(
    const int* __restrict__ sel3i, const float* __restrict__ sel3v,
    const float* __restrict__ w, float* __restrict__ u)
{
    int t = blockIdx.x * 256 + threadIdx.x;
    if (t >= NSEL) return;
    int j = (t / KSEL) % NB;
    int b = t / (KSEL * NB);
    int n = sel3i[t];
    float val = sel3v[t];
    atomicAdd(u + (size_t)n * NB + j, w[(size_t)n * BB + b] * val);
}

extern "C" void kernel_launch(void* const* d_in, const int* in_sizes, int n_in,
                              void* d_out, int out_size, void* d_ws, size_t ws_size,
                              hipStream_t stream)
{
    const float* tfeat      = (const float*)d_in[0];
    const float* dfeat      = (const float*)d_in[1];
    const float* alphaP     = (const float*)d_in[2];
    const float* emb1       = (const float*)d_in[3];
    const float* emb2       = (const float*)d_in[4];
    const float* lin1_w     = (const float*)d_in[5];
    const float* lin1_b     = (const float*)d_in[6];
    const float* lin2_w     = (const float*)d_in[7];
    const float* lin2_b     = (const float*)d_in[8];
    const float* in_proj_w  = (const float*)d_in[9];
    const float* in_proj_b  = (const float*)d_in[10];
    const float* out_proj_w = (const float*)d_in[11];
    const float* out_proj_b = (const float*)d_in[12];
    const float* noise1     = (const float*)d_in[13];
    const float* noise2     = (const float*)d_in[14];
    const float* noise3     = (const float*)d_in[15];
    float* out = (float*)d_out;

    const size_t NN  = NN_;               // 640000
    const size_t BNN = (size_t)BB * NN;   // 5120000

    float* ws  = (float*)d_ws;
    float* v1  = ws;              // BNN (later: u)
    float* v2  = v1 + BNN;        // BNN (later: g)
    float* Mb  = v2 + BNN;        // BNN (later: Wqt/Wkt)
    float* n1  = Mb + BNN;        // 32000
    float* n2  = n1 + NB * DIMM;  // 32000
    float* Qn  = n2 + NB * DIMM;  // NN
    float* Ob  = Qn + NN;         // NN
    float* a1v = Ob + NN;         // 16000
    int*   a1i = (int*)(a1v + NB * KSEL);       // 16000
    float* sel2v = (float*)(a1i + NB * KSEL);   // 128000
    int*   sel2i = (int*)(sel2v + NSEL);        // 128000
    float* sel3v = (float*)(sel2i + NSEL);      // 128000
    int*   sel3i = (int*)(sel3v + NSEL);        // 128000
    float* scores = (float*)(sel3i + NSEL);     // 6400
    float* wgt    = scores + NB * BB;           // 6400
    float* u  = v1;
    float* g  = v2;
    float* Wt = Mb;               // Wqt = Wt, Wkt = Wt + NN
    float* a2 = out;              // d_out as scratch until final gemm

    const float* bq = in_proj_b;

    lin_tanh_kernel<<<(NB * DIMM + 255) / 256, 256, 0, stream>>>(emb1, lin1_w, lin1_b, alphaP, n1);
    lin_tanh_kernel<<<(NB * DIMM + 255) / 256, 256, 0, stream>>>(emb2, lin2_w, lin2_b, alphaP, n2);
    adj1_topk_kernel<<<NB, 256, 0, stream>>>(n1, n2, alphaP, noise1, a1v, a1i);
    vgram_kernel<<<13 * 13 * BB, 256, 0, stream>>>(tfeat, v1);
    vgram_kernel<<<13 * 13 * BB, 256, 0, stream>>>(dfeat, v2);
    // M = v1 @ v2^T (batched, XCD-pinned)
    gemm_abt_kernel<<<13 * 13 * BB, 256, 0, stream>>>(
        v1, v2, nullptr, Mb, NB, NB, NB, (long)NN, (long)NN, (long)NN, 1, 0, 13, BB);
    antisym_kernel<<<dim3(25, 25, BB), 256, 0, stream>>>(Mb);
    topk2_tile_kernel<<<(NB / 4) * BB, 256, 0, stream>>>(Mb, noise2, a2, sel2i, sel2v);
    a3_tile_kernel<<<(NB / 4) * BB, 256, 0, stream>>>(a2, a1v, a1i, alphaP, noise3, sel3i, sel3v);
    // Wqt, Wkt (Mb dead after topk2)
    transpose_w_kernel<<<dim3(25, 25, 2), 256, 0, stream>>>(in_proj_w, Wt);
    qn_sparse_kernel<<<NB, 256, 0, stream>>>(a1v, a1i, Wt, bq, Qn);
    // g = Qn @ Wk  (= gemm_abt(Qn, Wkt))
    gemm_abt_kernel<<<13 * 13, 256, 0, stream>>>(
        Qn, Wt + NN, nullptr, g, NB, NB, NB, 0, 0, 0, 1, 0, 13, 1);
    hipMemsetAsync(scores, 0, NB * BB * sizeof(float), stream);
    scatter_scores_kernel<<<NSEL / 256, 256, 0, stream>>>(sel2i, sel2v, g, scores);
    softmax_w_kernel<<<(NB + 255) / 256, 256, 0, stream>>>(scores, wgt);
    hipMemsetAsync(u, 0, NN * sizeof(float), stream);
    scatter_u_kernel<<<NSEL / 256, 256, 0, stream>>>(sel3i, sel3v, wgt, u);
    // O = u @ Wv^T + bv
    gemm_abt_kernel<<<13 * 13, 256, 0, stream>>>(
        u, in_proj_w + 2 * NN, in_proj_b + 2 * NB, Ob, NB, NB, NB, 0, 0, 0, 1, 0, 13, 1);
    // out = O @ Wout^T + bout, broadcast to 8 copies
    gemm_abt_kernel<<<13 * 13, 256, 0, stream>>>(
        Ob, out_proj_w, out_proj_b, out, NB, NB, NB, 0, 0, 0, BB, (long)NN, 13, 1);
}

// Round 7
// 850.903 us; speedup vs baseline: 2.0869x; 1.0740x over previous
//
#include <hip/hip_runtime.h>
#include <cmath>

#define NB 800
#define BB 8
#define FF 12
#define DD 32
#define DIMM 40
#define KSEL 20
#define NN_ ((size_t)NB * NB)
#define NSEL (BB * NB * KSEL)

// two-step mul-add with contraction barrier: matches numpy's round(v + round(0.01*n))
__device__ __forceinline__ float score_f32(float v, float n) {
    float p = 0.01f * n;
    asm volatile("" : "+v"(p));
    return v + p;
}

// n = tanh(alpha * (emb @ W^T + b)) : (800,40)
__global__ __launch_bounds__(256) void lin_tanh_kernel(
    const float* __restrict__ emb, const float* __restrict__ W,
    const float* __restrict__ bias, const float* __restrict__ alphaP,
    float* __restrict__ out)
{
    int idx = blockIdx.x * 256 + threadIdx.x;
    if (idx >= NB * DIMM) return;
    int i = idx / DIMM, m = idx - i * DIMM;
    float acc = 0.f;
    #pragma unroll
    for (int d = 0; d < DIMM; ++d) acc += emb[i * DIMM + d] * W[m * DIMM + d];
    acc += bias[m];
    out[idx] = tanhf(alphaP[0] * acc);
}

// Fused adj1 + row top-K, f32 quantized scoring + lowest-index ties.
__global__ __launch_bounds__(256) void adj1_topk_kernel(
    const float* __restrict__ n1, const float* __restrict__ n2,
    const float* __restrict__ alphaP, const float* __restrict__ noise,
    float* __restrict__ a1val, int* __restrict__ a1idx)
{
    int i = blockIdx.x;
    int tid = threadIdx.x;
    __shared__ float vals[NB];
    __shared__ float sc[NB];
    __shared__ float redV[256];
    __shared__ int   redI[256];
    __shared__ int   sel[KSEL];
    __shared__ float n1i[DIMM], n2i[DIMM];
    if (tid < DIMM) { n1i[tid] = n1[i * DIMM + tid]; n2i[tid] = n2[i * DIMM + tid]; }
    __syncthreads();
    float alpha = alphaP[0];
    for (int j = tid; j < NB; j += 256) {
        float s1 = 0.f, s2 = 0.f;
        #pragma unroll
        for (int d = 0; d < DIMM; ++d) {
            s1 += n1i[d] * n2[j * DIMM + d];
            s2 += n2i[d] * n1[j * DIMM + d];
        }
        float t = tanhf(alpha * (s1 - s2));
        float v = t > 0.f ? t : 0.f;
        vals[j] = v;
        sc[j] = score_f32(v, noise[(size_t)i * NB + j]);
    }
    __syncthreads();
    for (int t = 0; t < KSEL; ++t) {
        float bv = -2.0e30f; int bi = NB;
        for (int j = tid; j < NB; j += 256) {
            float s = sc[j];
            if (s > bv || (s == bv && j < bi)) { bv = s; bi = j; }
        }
        redV[tid] = bv; redI[tid] = bi;
        __syncthreads();
        for (int s2 = 128; s2 > 0; s2 >>= 1) {
            if (tid < s2) {
                float ov = redV[tid + s2]; int oi = redI[tid + s2];
                if (ov > redV[tid] || (ov == redV[tid] && oi < redI[tid])) {
                    redV[tid] = ov; redI[tid] = oi;
                }
            }
            __syncthreads();
        }
        if (tid == 0) { sel[t] = redI[0]; sc[redI[0]] = -1.0e30f; }
        __syncthreads();
    }
    if (tid == 0) {
        int tmp[KSEL];
        #pragma unroll
        for (int t = 0; t < KSEL; ++t) tmp[t] = sel[t];
        for (int a = 1; a < KSEL; ++a) {
            int key = tmp[a]; int b = a - 1;
            while (b >= 0 && tmp[b] > key) { tmp[b + 1] = tmp[b]; --b; }
            tmp[b + 1] = key;
        }
        for (int t = 0; t < KSEL; ++t) {
            a1idx[i * KSEL + t] = tmp[t];
            a1val[i * KSEL + t] = vals[tmp[t]];
        }
    }
}

// In-place antisymmetrization: M <- M - M^T, XCD-pinned 1-D grid (b = bid&7).
__global__ __launch_bounds__(256) void antisym_kernel(float* __restrict__ M)
{
    int bid = blockIdx.x;
    int b = bid & 7;
    int t_ = bid >> 3;
    int ti = t_ / 25, tj = t_ % 25;
    if (ti > tj) return;
    float* Mb_ = M + (size_t)b * NN_;
    __shared__ float T1[32][33];
    __shared__ float T2[32][33];
    int tid = threadIdx.x;
    int r = tid >> 3, c4 = (tid & 7) * 4;
    int i0 = ti * 32, j0 = tj * 32;
    float4 x1 = *(const float4*)(Mb_ + (size_t)(i0 + r) * NB + j0 + c4);
    float4 x2 = *(const float4*)(Mb_ + (size_t)(j0 + r) * NB + i0 + c4);
    T1[r][c4] = x1.x; T1[r][c4 + 1] = x1.y; T1[r][c4 + 2] = x1.z; T1[r][c4 + 3] = x1.w;
    T2[r][c4] = x2.x; T2[r][c4 + 1] = x2.y; T2[r][c4 + 2] = x2.z; T2[r][c4 + 3] = x2.w;
    __syncthreads();
    float4 d1;
    d1.x = T1[r][c4 + 0] - T2[c4 + 0][r];
    d1.y = T1[r][c4 + 1] - T2[c4 + 1][r];
    d1.z = T1[r][c4 + 2] - T2[c4 + 2][r];
    d1.w = T1[r][c4 + 3] - T2[c4 + 3][r];
    *(float4*)(Mb_ + (size_t)(i0 + r) * NB + j0 + c4) = d1;
    if (ti != tj) {
        float4 d2;
        d2.x = T2[r][c4 + 0] - T1[c4 + 0][r];
        d2.y = T2[r][c4 + 1] - T1[c4 + 1][r];
        d2.z = T2[r][c4 + 2] - T1[c4 + 2][r];
        d2.w = T2[r][c4 + 3] - T1[c4 + 3][r];
        *(float4*)(Mb_ + (size_t)(j0 + r) * NB + i0 + c4) = d2;
    }
}

// Column top-K of adj2, 4 columns/block, XCD-pinned (b = bid&7). Per-wave scan
// (64-lane groups, no per-round barrier), values in registers.
__global__ __launch_bounds__(256) void topk2_tile_kernel(
    const float* __restrict__ adj2, const float* __restrict__ noise,
    float* __restrict__ outp, int* __restrict__ sel2i, float* __restrict__ sel2v)
{
    int bid = blockIdx.x;
    int b = bid & 7;
    int j0 = (bid >> 3) * 4;
    int tid = threadIdx.x;
    const float* Ab = adj2 + (size_t)b * NN_;
    const float* Zb = noise + (size_t)b * NN_;
    float* Ob = outp + (size_t)b * NN_;
    __shared__ float sc[NB][5];
    __shared__ int selIdx[4][KSEL];
    float4 myval[4];
    #pragma unroll
    for (int k = 0; k < 4; ++k) {
        int i = tid + k * 256;
        if (i < NB) {
            float4 v  = *(const float4*)(Ab + (size_t)i * NB + j0);
            float4 nz = *(const float4*)(Zb + (size_t)i * NB + j0);
            myval[k] = v;
            sc[i][0] = score_f32(v.x, nz.x);
            sc[i][1] = score_f32(v.y, nz.y);
            sc[i][2] = score_f32(v.z, nz.z);
            sc[i][3] = score_f32(v.w, nz.w);
        }
    }
    __syncthreads();
    int g = tid >> 6, l = tid & 63;
    size_t lbase = ((size_t)b * NB + (j0 + g)) * KSEL;
    for (int t = 0; t < KSEL; ++t) {
        float bv = -2.0e30f; int bi = NB;
        for (int i = l; i < NB; i += 64) {
            float s = sc[i][g];
            if (s > bv || (s == bv && i < bi)) { bv = s; bi = i; }
        }
        #pragma unroll
        for (int m = 32; m >= 1; m >>= 1) {
            float ov = __shfl_xor(bv, m, 64);
            int   oi = __shfl_xor(bi, m, 64);
            if (ov > bv || (ov == bv && oi < bi)) { bv = ov; bi = oi; }
        }
        if (l == 0) {
            sc[bi][g] = -1.0e30f;   // tombstone = selection mark (intra-wave visible)
            selIdx[g][t] = bi;
            sel2i[lbase + t] = bi;
        }
    }
    __syncthreads();
    #pragma unroll
    for (int k = 0; k < 4; ++k) {
        int i = tid + k * 256;
        if (i >= NB) continue;
        float vv[4] = {myval[k].x, myval[k].y, myval[k].z, myval[k].w};
        float o4[4];
        #pragma unroll
        for (int c = 0; c < 4; ++c) {
            bool seld = (sc[i][c] == -1.0e30f);
            o4[c] = seld ? vv[c] : 0.f;
            if (seld) {
                int rk = 0;
                for (int t = 0; t < KSEL; ++t) if (selIdx[c][t] == i) rk = t;
                sel2v[((size_t)b * NB + (j0 + c)) * KSEL + rk] = vv[c];
            }
        }
        *(float4*)(Ob + (size_t)i * NB + j0) = make_float4(o4[0], o4[1], o4[2], o4[3]);
    }
}

// Dense a3 values, row-streaming: a3v[b,i,:] = relu(tanh(alpha * sum_t
// a1val[i,t]*a2[b,a1idx[i,t],:])). Coalesced full-row reads, XCD-pinned.
__global__ __launch_bounds__(256) void a3dense_kernel(
    const float* __restrict__ a2, const float* __restrict__ a1val,
    const int* __restrict__ a1idx, const float* __restrict__ alphaP,
    float* __restrict__ a3v)
{
    int bid = blockIdx.x;
    int b = bid & 7;
    int i = bid >> 3;
    int tid = threadIdx.x;
    __shared__ float sval[KSEL];
    __shared__ int   sidx[KSEL];
    if (tid < KSEL) { sval[tid] = a1val[i * KSEL + tid]; sidx[tid] = a1idx[i * KSEL + tid]; }
    __syncthreads();
    if (tid >= 200) return;
    float alpha = alphaP[0];
    const float* a2b = a2 + (size_t)b * NN_;
    int j = tid * 4;
    float4 acc = make_float4(0.f, 0.f, 0.f, 0.f);
    #pragma unroll
    for (int t = 0; t < KSEL; ++t) {
        float vt = sval[t];
        float4 s = *(const float4*)(a2b + (size_t)sidx[t] * NB + j);
        acc.x = fmaf(vt, s.x, acc.x);
        acc.y = fmaf(vt, s.y, acc.y);
        acc.z = fmaf(vt, s.z, acc.z);
        acc.w = fmaf(vt, s.w, acc.w);
    }
    float4 th;
    th.x = tanhf(alpha * acc.x); th.y = tanhf(alpha * acc.y);
    th.z = tanhf(alpha * acc.z); th.w = tanhf(alpha * acc.w);
    th.x = th.x > 0.f ? th.x : 0.f;
    th.y = th.y > 0.f ? th.y : 0.f;
    th.z = th.z > 0.f ? th.z : 0.f;
    th.w = th.w > 0.f ? th.w : 0.f;
    *(float4*)(a3v + (size_t)b * NN_ + (size_t)i * NB + j) = th;
}

// Column top-K of precomputed a3v, 4 columns/block, XCD-pinned. Emits sel lists only.
__global__ __launch_bounds__(256) void a3topk_tile_kernel(
    const float* __restrict__ a3v, const float* __restrict__ noise,
    int* __restrict__ sel3i, float* __restrict__ sel3v)
{
    int bid = blockIdx.x;
    int b = bid & 7;
    int j0 = (bid >> 3) * 4;
    int tid = threadIdx.x;
    const float* Ab = a3v + (size_t)b * NN_;
    const float* Zb = noise + (size_t)b * NN_;
    __shared__ float sc[NB][5];
    __shared__ int selIdx[4][KSEL];
    float4 myval[4];
    #pragma unroll
    for (int k = 0; k < 4; ++k) {
        int i = tid + k * 256;
        if (i < NB) {
            float4 v  = *(const float4*)(Ab + (size_t)i * NB + j0);
            float4 nz = *(const float4*)(Zb + (size_t)i * NB + j0);
            myval[k] = v;
            sc[i][0] = score_f32(v.x, nz.x);
            sc[i][1] = score_f32(v.y, nz.y);
            sc[i][2] = score_f32(v.z, nz.z);
            sc[i][3] = score_f32(v.w, nz.w);
        }
    }
    __syncthreads();
    int g = tid >> 6, l = tid & 63;
    size_t lbase = ((size_t)b * NB + (j0 + g)) * KSEL;
    for (int t = 0; t < KSEL; ++t) {
        float bv = -2.0e30f; int bi = NB;
        for (int i = l; i < NB; i += 64) {
            float s = sc[i][g];
            if (s > bv || (s == bv && i < bi)) { bv = s; bi = i; }
        }
        #pragma unroll
        for (int m = 32; m >= 1; m >>= 1) {
            float ov = __shfl_xor(bv, m, 64);
            int   oi = __shfl_xor(bi, m, 64);
            if (ov > bv || (ov == bv && oi < bi)) { bv = ov; bi = oi; }
        }
        if (l == 0) {
            sc[bi][g] = -1.0e30f;
            selIdx[g][t] = bi;
            sel3i[lbase + t] = bi;
        }
    }
    __syncthreads();
    #pragma unroll
    for (int k = 0; k < 4; ++k) {
        int i = tid + k * 256;
        if (i >= NB) continue;
        float vv[4] = {myval[k].x, myval[k].y, myval[k].z, myval[k].w};
        #pragma unroll
        for (int c = 0; c < 4; ++c) {
            if (sc[i][c] == -1.0e30f) {
                int rk = 0;
                for (int t = 0; t < KSEL; ++t) if (selIdx[c][t] == i) rk = t;
                sel3v[((size_t)b * NB + (j0 + c)) * KSEL + rk] = vv[c];
            }
        }
    }
}

// v[b,i,j] = tanh((sum_f sum_d x[b,f,i,d]*x[b,f,j,d])/F), 64x64 tile, k-major
// LDS, XCD-pinned 1-D grid.
__global__ __launch_bounds__(256) void vgram_kernel(
    const float* __restrict__ x, float* __restrict__ v)
{
    int bid = blockIdx.x;
    int b = bid & 7;
    int t_ = bid >> 3;
    int i0 = (t_ / 13) * 64, j0 = (t_ % 13) * 64;
    int tid = threadIdx.x;
    int tx = tid & 15, ty = tid >> 4;
    __shared__ __align__(16) float XiT[DD][68];
    __shared__ __align__(16) float XjT[DD][68];
    float acc[4][4] = {};
    for (int f = 0; f < FF; ++f) {
        const float* base = x + ((size_t)b * FF + f) * NB * DD;
        #pragma unroll
        for (int l = 0; l < 2; ++l) {
            int s = tid + l * 256;
            int r = s >> 3, c4 = (s & 7) * 4;
            int ri = i0 + r; if (ri > NB - 1) ri = NB - 1;
            float4 va = *(const float4*)(base + (size_t)ri * DD + c4);
            XiT[c4 + 0][r] = va.x; XiT[c4 + 1][r] = va.y; XiT[c4 + 2][r] = va.z; XiT[c4 + 3][r] = va.w;
            int rj = j0 + r; if (rj > NB - 1) rj = NB - 1;
            float4 vb = *(const float4*)(base + (size_t)rj * DD + c4);
            XjT[c4 + 0][r] = vb.x; XjT[c4 + 1][r] = vb.y; XjT[c4 + 2][r] = vb.z; XjT[c4 + 3][r] = vb.w;
        }
        __syncthreads();
        #pragma unroll 8
        for (int d = 0; d < DD; ++d) {
            float4 a4 = *(const float4*)&XiT[d][ty * 4];
            float4 b4 = *(const float4*)&XjT[d][tx * 4];
            acc[0][0] += a4.x * b4.x; acc[0][1] += a4.x * b4.y; acc[0][2] += a4.x * b4.z; acc[0][3] += a4.x * b4.w;
            acc[1][0] += a4.y * b4.x; acc[1][1] += a4.y * b4.y; acc[1][2] += a4.y * b4.z; acc[1][3] += a4.y * b4.w;
            acc[2][0] += a4.z * b4.x; acc[2][1] += a4.z * b4.y; acc[2][2] += a4.z * b4.z; acc[2][3] += a4.z * b4.w;
            acc[3][0] += a4.w * b4.x; acc[3][1] += a4.w * b4.y; acc[3][2] += a4.w * b4.z; acc[3][3] += a4.w * b4.w;
        }
        __syncthreads();
    }
    size_t basev = (size_t)b * NN_;
    int j = j0 + tx * 4;
    if (j >= NB) return;
    #pragma unroll
    for (int m = 0; m < 4; ++m) {
        int i = i0 + ty * 4 + m;
        if (i >= NB) continue;
        float4 o;
        o.x = tanhf(acc[m][0] / 12.0f);
        o.y = tanhf(acc[m][1] / 12.0f);
        o.z = tanhf(acc[m][2] / 12.0f);
        o.w = tanhf(acc[m][3] / 12.0f);
        *(float4*)(v + basev + (size_t)i * NB + j) = o;
    }
}

// C[b,i,j] = sum_k A[b,i,k]*B[b,j,k] (+bias[j]), replicated nCopies times.
// k-major LDS tiles (BK=32), XCD-pinned 1-D grid decode (bz = bid % nBatch).
__global__ __launch_bounds__(256) void gemm_abt_kernel(
    const float* __restrict__ A, const float* __restrict__ B,
    const float* __restrict__ bias, float* __restrict__ C,
    int M, int Nn, int Kk,
    long aStride, long bStride, long cStride,
    int nCopies, long copyStride, int tilesX, int nBatch)
{
    int bid = blockIdx.x;
    int bz = bid % nBatch;
    int t_ = bid / nBatch;
    int j0 = (t_ % tilesX) * 64;
    int i0 = (t_ / tilesX) * 64;
    const float* Ab = A + (size_t)bz * aStride;
    const float* Bb = B + (size_t)bz * bStride;
    float* Cb = C + (size_t)bz * cStride;
    int tid = threadIdx.x;
    int tx = tid & 15, ty = tid >> 4;
    __shared__ __align__(16) float AsT[32][68];
    __shared__ __align__(16) float BsT[32][68];
    float acc[4][4] = {};
    for (int kt = 0; kt < Kk; kt += 32) {
        #pragma unroll
        for (int l = 0; l < 2; ++l) {
            int s = tid + l * 256;
            int r = s >> 3, c4 = (s & 7) * 4;
            int ai = i0 + r;
            float4 va = make_float4(0.f, 0.f, 0.f, 0.f);
            if (ai < M) va = *(const float4*)(Ab + (size_t)ai * Kk + kt + c4);
            AsT[c4 + 0][r] = va.x; AsT[c4 + 1][r] = va.y; AsT[c4 + 2][r] = va.z; AsT[c4 + 3][r] = va.w;
            int bj = j0 + r;
            float4 vb = make_float4(0.f, 0.f, 0.f, 0.f);
            if (bj < Nn) vb = *(const float4*)(Bb + (size_t)bj * Kk + kt + c4);
            BsT[c4 + 0][r] = vb.x; BsT[c4 + 1][r] = vb.y; BsT[c4 + 2][r] = vb.z; BsT[c4 + 3][r] = vb.w;
        }
        __syncthreads();
        #pragma unroll 8
        for (int kk = 0; kk < 32; ++kk) {
            float4 a4 = *(const float4*)&AsT[kk][ty * 4];
            float4 b4 = *(const float4*)&BsT[kk][tx * 4];
            acc[0][0] += a4.x * b4.x; acc[0][1] += a4.x * b4.y; acc[0][2] += a4.x * b4.z; acc[0][3] += a4.x * b4.w;
            acc[1][0] += a4.y * b4.x; acc[1][1] += a4.y * b4.y; acc[1][2] += a4.y * b4.z; acc[1][3] += a4.y * b4.w;
            acc[2][0] += a4.z * b4.x; acc[2][1] += a4.z * b4.y; acc[2][2] += a4.z * b4.z; acc[2][3] += a4.z * b4.w;
            acc[3][0] += a4.w * b4.x; acc[3][1] += a4.w * b4.y; acc[3][2] += a4.w * b4.z; acc[3][3] += a4.w * b4.w;
        }
        __syncthreads();
    }
    int j = j0 + tx * 4;
    if (j >= Nn) return;
    #pragma unroll
    for (int m = 0; m < 4; ++m) {
        int i = i0 + ty * 4 + m;
        if (i >= M) continue;
        float4 o;
        o.x = acc[m][0] + (bias ? bias[j + 0] : 0.f);
        o.y = acc[m][1] + (bias ? bias[j + 1] : 0.f);
        o.z = acc[m][2] + (bias ? bias[j + 2] : 0.f);
        o.w = acc[m][3] + (bias ? bias[j + 3] : 0.f);
        for (int c = 0; c < nCopies; ++c)
            *(float4*)(Cb + (size_t)c * copyStride + (size_t)i * Nn + j) = o;
    }
}

// Wt[z][j][e] = W[z][e][j] for z=0(Wq),1(Wk)
__global__ __launch_bounds__(256) void transpose_w_kernel(
    const float* __restrict__ W, float* __restrict__ Wt)
{
    int z = blockIdx.z;
    const float* in = W + (size_t)z * NN_;
    float* outp = Wt + (size_t)z * NN_;
    __shared__ float T[32][33];
    int e0 = blockIdx.y * 32, j0 = blockIdx.x * 32;
    int tid = threadIdx.x;
    int r = tid >> 3, c4 = (tid & 7) * 4;
    float4 v = *(const float4*)(in + (size_t)(e0 + r) * NB + j0 + c4);
    T[r][c4 + 0] = v.x; T[r][c4 + 1] = v.y; T[r][c4 + 2] = v.z; T[r][c4 + 3] = v.w;
    __syncthreads();
    float4 o;
    o.x = T[c4 + 0][r]; o.y = T[c4 + 1][r]; o.z = T[c4 + 2][r]; o.w = T[c4 + 3][r];
    *(float4*)(outp + (size_t)(j0 + r) * NB + e0 + c4) = o;
}

// Qn[i,:] = sum_t a1val[i,t]*Wqt[a1idx[i,t],:] + bq
__global__ __launch_bounds__(256) void qn_sparse_kernel(
    const float* __restrict__ a1v, const int* __restrict__ a1i,
    const float* __restrict__ Wqt, const float* __restrict__ bq,
    float* __restrict__ Qn)
{
    int i = blockIdx.x;
    int tid = threadIdx.x;
    __shared__ float sval[KSEL];
    __shared__ int   sidx[KSEL];
    if (tid < KSEL) { sval[tid] = a1v[i * KSEL + tid]; sidx[tid] = a1i[i * KSEL + tid]; }
    __syncthreads();
    for (int e = tid; e < NB; e += 256) {
        float acc = 0.f;
        #pragma unroll
        for (int t = 0; t < KSEL; ++t)
            acc = fmaf(sval[t], Wqt[(size_t)sidx[t] * NB + e], acc);
        Qn[(size_t)i * NB + e] = acc + bq[e];
    }
}

// scores[n,b] += a2val * g[n,j] over a2's selected entries
__global__ __launch_bounds__(256) void scatter_scores_kernel(
    const int* __restrict__ sel2i, const float* __restrict__ sel2v,
    const float* __restrict__ g, float* __restrict__ scores)
{
    int t = blockIdx.x * 256 + threadIdx.x;
    if (t >= NSEL) return;
    int j = (t / KSEL) % NB;
    int b = t / (KSEL * NB);
    int n = sel2i[t];
    float val = sel2v[t];
    atomicAdd(scores + (size_t)n * BB + b, val * g[(size_t)n * NB + j]);
}

// w[n,:] = softmax(scores[n,:]/sqrt(800))
__global__ __launch_bounds__(256) void softmax_w_kernel(
    const float* __restrict__ scores, float* __restrict__ w)
{
    int n = blockIdx.x * 256 + threadIdx.x;
    if (n >= NB) return;
    float s[BB];
    float mx = -INFINITY;
    for (int k = 0; k < BB; ++k) {
        s[k] = scores[(size_t)n * BB + k] / sqrtf(800.0f);
        if (s[k] > mx) mx = s[k];
    }
    float sum = 0.f;
    for (int k = 0; k < BB; ++k) { s[k] = expf(s[k] - mx); sum += s[k]; }
    for (int k = 0; k < BB; ++k) w[(size_t)n * BB + k] = s[k] / sum;
}

// u[n,j] += w[n,b] * a3val over a3's selected entries
__global__ __launch_bounds__(256) void scatter_u_kernel(
    const int* __restrict__ sel3i, const float* __restrict__ sel3v,
    const float* __restrict__ w, float* __restrict__ u)
{
    int t = blockIdx.x * 256 + threadIdx.x;
    if (t >= NSEL) return;
    int j = (t / KSEL) % NB;
    int b = t / (KSEL * NB);
    int n = sel3i[t];
    float val = sel3v[t];
    atomicAdd(u + (size_t)n * NB + j, w[(size_t)n * BB + b] * val);
}

extern "C" void kernel_launch(void* const* d_in, const int* in_sizes, int n_in,
                              void* d_out, int out_size, void* d_ws, size_t ws_size,
                              hipStream_t stream)
{
    const float* tfeat      = (const float*)d_in[0];
    const float* dfeat      = (const float*)d_in[1];
    const float* alphaP     = (const float*)d_in[2];
    const float* emb1       = (const float*)d_in[3];
    const float* emb2       = (const float*)d_in[4];
    const float* lin1_w     = (const float*)d_in[5];
    const float* lin1_b     = (const float*)d_in[6];
    const float* lin2_w     = (const float*)d_in[7];
    const float* lin2_b     = (const float*)d_in[8];
    const float* in_proj_w  = (const float*)d_in[9];
    const float* in_proj_b  = (const float*)d_in[10];
    const float* out_proj_w = (const float*)d_in[11];
    const float* out_proj_b = (const float*)d_in[12];
    const float* noise1     = (const float*)d_in[13];
    const float* noise2     = (const float*)d_in[14];
    const float* noise3     = (const float*)d_in[15];
    float* out = (float*)d_out;

    const size_t NN  = NN_;               // 640000
    const size_t BNN = (size_t)BB * NN;   // 5120000

    float* ws  = (float*)d_ws;
    float* v1  = ws;              // BNN (later: u)
    float* v2  = v1 + BNN;        // BNN (later: g)
    float* Mb  = v2 + BNN;        // BNN (adj2 -> a3v -> Wqt/Wkt)
    float* n1  = Mb + BNN;        // 32000
    float* n2  = n1 + NB * DIMM;  // 32000
    float* Qn  = n2 + NB * DIMM;  // NN
    float* Ob  = Qn + NN;         // NN
    float* a1v = Ob + NN;         // 16000
    int*   a1i = (int*)(a1v + NB * KSEL);       // 16000
    float* sel2v = (float*)(a1i + NB * KSEL);   // 128000
    int*   sel2i = (int*)(sel2v + NSEL);        // 128000
    float* sel3v = (float*)(sel2i + NSEL);      // 128000
    int*   sel3i = (int*)(sel3v + NSEL);        // 128000
    float* scores = (float*)(sel3i + NSEL);     // 6400
    float* wgt    = scores + NB * BB;           // 6400
    float* u   = v1;
    float* g   = v2;
    float* a3v = Mb;              // reuse: adj2 dead after topk2
    float* Wt  = Mb;              // reuse: a3v dead after a3topk
    float* a2  = out;             // d_out as scratch until final gemm

    const float* bq = in_proj_b;

    lin_tanh_kernel<<<(NB * DIMM + 255) / 256, 256, 0, stream>>>(emb1, lin1_w, lin1_b, alphaP, n1);
    lin_tanh_kernel<<<(NB * DIMM + 255) / 256, 256, 0, stream>>>(emb2, lin2_w, lin2_b, alphaP, n2);
    adj1_topk_kernel<<<NB, 256, 0, stream>>>(n1, n2, alphaP, noise1, a1v, a1i);
    vgram_kernel<<<13 * 13 * BB, 256, 0, stream>>>(tfeat, v1);
    vgram_kernel<<<13 * 13 * BB, 256, 0, stream>>>(dfeat, v2);
    // M = v1 @ v2^T (batched, XCD-pinned)
    gemm_abt_kernel<<<13 * 13 * BB, 256, 0, stream>>>(
        v1, v2, nullptr, Mb, NB, NB, NB, (long)NN, (long)NN, (long)NN, 1, 0, 13, BB);
    antisym_kernel<<<25 * 25 * BB, 256, 0, stream>>>(Mb);
    topk2_tile_kernel<<<(NB / 4) * BB, 256, 0, stream>>>(Mb, noise2, a2, sel2i, sel2v);
    // a3 values (dense rows, streamed) then column top-K
    a3dense_kernel<<<NB * BB, 256, 0, stream>>>(a2, a1v, a1i, alphaP, a3v);
    a3topk_tile_kernel<<<(NB / 4) * BB, 256, 0, stream>>>(a3v, noise3, sel3i, sel3v);
    // Wqt, Wkt (a3v dead)
    transpose_w_kernel<<<dim3(25, 25, 2), 256, 0, stream>>>(in_proj_w, Wt);
    qn_sparse_kernel<<<NB, 256, 0, stream>>>(a1v, a1i, Wt, bq, Qn);
    // g = Qn @ Wk  (= gemm_abt(Qn, Wkt))
    gemm_abt_kernel<<<13 * 13, 256, 0, stream>>>(
        Qn, Wt + NN, nullptr, g, NB, NB, NB, 0, 0, 0, 1, 0, 13, 1);
    hipMemsetAsync(scores, 0, NB * BB * sizeof(float), stream);
    scatter_scores_kernel<<<NSEL / 256, 256, 0, stream>>>(sel2i, sel2v, g, scores);
    softmax_w_kernel<<<(NB + 255) / 256, 256, 0, stream>>>(scores, wgt);
    hipMemsetAsync(u, 0, NN * sizeof(float), stream);
    scatter_u_kernel<<<NSEL / 256, 256, 0, stream>>>(sel3i, sel3v, wgt, u);
    // O = u @ Wv^T + bv
    gemm_abt_kernel<<<13 * 13, 256, 0, stream>>>(
        u, in_proj_w + 2 * NN, in_proj_b + 2 * NB, Ob, NB, NB, NB, 0, 0, 0, 1, 0, 13, 1);
    // out = O @ Wout^T + bout, broadcast to 8 copies
    gemm_abt_kernel<<<13 * 13, 256, 0, stream>>>(
        Ob, out_proj_w, out_proj_b, out, NB, NB, NB, 0, 0, 0, BB, (long)NN, 13, 1);
}